// Round 8
// baseline (383.065 us; speedup 1.0000x reference)
//
#include <hip/hip_runtime.h>
#include <cstdint>

typedef unsigned short ushort_t;
typedef __attribute__((ext_vector_type(4))) unsigned short ushort4_t;
typedef __attribute__((ext_vector_type(8))) unsigned short ushort8_t;
typedef __attribute__((ext_vector_type(8))) __bf16 bf16x8;
typedef __attribute__((ext_vector_type(4))) float f32x4;

constexpr int NB = 16;    // batch
constexpr int NC = 256;   // channels C (== E)
constexpr int NN = 4096;  // tokens N = H*W
constexpr int NP = 1024;  // region-proj channels = 2*R*heads
constexpr int NT = 512;   // heads * R (Rq columns of T)
constexpr int NO = 768;   // 3*E rows of Wqkv

static __device__ __forceinline__ ushort_t f2b(float f) {
  uint32_t u = __builtin_bit_cast(uint32_t, f);
  u += 0x7FFFu + ((u >> 16) & 1u);
  return (ushort_t)(u >> 16);
}
static __device__ __forceinline__ float b2f(ushort_t h) {
  return __builtin_bit_cast(float, (uint32_t)h << 16);
}
static __device__ __forceinline__ f32x4 mfma16(bf16x8 a, bf16x8 b, f32x4 c) {
  return __builtin_amdgcn_mfma_f32_16x16x32_bf16(a, b, c, 0, 0, 0);
}
typedef __attribute__((address_space(1))) const unsigned int guint;
typedef __attribute__((address_space(3))) unsigned int luint;
static __device__ __forceinline__ void glds16(const void* g, void* l) {
  __builtin_amdgcn_global_load_lds((guint*)g, (luint*)l, 16, 0, 0);
}

// ---------------------------------------------------------------------------
// Single-buffer 128x128 GEMM core (m97-style): BK=64, XOR-swizzled LDS,
// 2 barriers per K-step. SH = 32 KB (As at 0, Bs at 8192 elems).
// ---------------------------------------------------------------------------
template <int KITERS>
__device__ __forceinline__ void gemm_core_sb(const ushort_t* __restrict__ Asrc, size_t lda,
                                             const ushort_t* __restrict__ Bsrc, size_t ldb,
                                             ushort_t* SH, f32x4 (&acc)[4][4], int tid) {
  const int l = tid & 63, w = tid >> 6;
  const int fr = l & 15, kq = (l >> 4) * 8;
  const int rr = l >> 3;
  const int sc = ((l & 7) ^ rr) << 3;
  const int swz = (fr & 7) << 3;
  const int wm = (w >> 1) * 64, wn = (w & 1) * 64;
  ushort_t* As = SH;
  ushort_t* Bs = SH + 8192;
#pragma unroll 1
  for (int it = 0; it < KITERS; it++) {
    const size_t k0 = (size_t)it * 64;
#pragma unroll
    for (int i = 0; i < 4; i++) {
      const int row = i * 32 + w * 8 + rr;
      glds16(Asrc + (size_t)row * lda + k0 + sc, As + (i * 32 + w * 8) * 64);
      glds16(Bsrc + (size_t)row * ldb + k0 + sc, Bs + (i * 32 + w * 8) * 64);
    }
    __syncthreads();
#pragma unroll
    for (int ks = 0; ks < 2; ks++) {
      const int col = ks * 32 + kq;
      bf16x8 af[4], bf[4];
#pragma unroll
      for (int f = 0; f < 4; f++) {
        af[f] = *(const bf16x8*)&As[(wm + f * 16 + fr) * 64 + (col ^ swz)];
        bf[f] = *(const bf16x8*)&Bs[(wn + f * 16 + fr) * 64 + (col ^ swz)];
      }
#pragma unroll
      for (int fm = 0; fm < 4; fm++)
#pragma unroll
        for (int fn = 0; fn < 4; fn++)
          acc[fm][fn] = mfma16(af[fm], bf[fn], acc[fm][fn]);
    }
    __syncthreads();
  }
}

// ---------------------------------------------------------------------------
// K0: x (f32 [b][c][n]) -> xb (bf16 [b][c][n]) and xt (bf16 [b][n][c])
// ---------------------------------------------------------------------------
__global__ __launch_bounds__(256) void k0_cvt(const float* __restrict__ x,
                                              ushort_t* __restrict__ xb,
                                              ushort_t* __restrict__ xt) {
  __shared__ ushort_t tr[64][88];
  const int tid = threadIdx.x;
  const int n0 = blockIdx.x * 64, c0 = blockIdx.y * 64, b = blockIdx.z;
  const int cr = (tid >> 4) * 4;
  const int nc4 = (tid & 15) * 4;
#pragma unroll
  for (int i = 0; i < 4; i++) {
    size_t idx = ((size_t)b * NC + c0 + cr + i) * NN + n0 + nc4;
    float4 v = *(const float4*)(x + idx);
    ushort4_t o;
    o[0] = f2b(v.x); o[1] = f2b(v.y); o[2] = f2b(v.z); o[3] = f2b(v.w);
    *(ushort4_t*)(xb + idx) = o;
    tr[nc4 + 0][cr + i] = o[0];
    tr[nc4 + 1][cr + i] = o[1];
    tr[nc4 + 2][cr + i] = o[2];
    tr[nc4 + 3][cr + i] = o[3];
  }
  __syncthreads();
  const int nr = tid >> 2, cc0 = (tid & 3) * 16;
  size_t odx = ((size_t)b * NN + n0 + nr) * NC + c0 + cc0;
  *(ushort8_t*)(xt + odx) = *(const ushort8_t*)&tr[nr][cc0];
  *(ushort8_t*)(xt + odx + 8) = *(const ushort8_t*)&tr[nr][cc0 + 8];
}

// generic f32 -> bf16 (count multiple of 1024)
__global__ __launch_bounds__(256) void cvt_f2b_k(const float* __restrict__ src,
                                                 ushort_t* __restrict__ dst) {
  int i = (blockIdx.x * 256 + threadIdx.x) * 4;
  float4 v = *(const float4*)(src + i);
  ushort4_t o;
  o[0] = f2b(v.x); o[1] = f2b(v.y); o[2] = f2b(v.z); o[3] = f2b(v.w);
  *(ushort4_t*)(dst + i) = o;
}

// ---------------------------------------------------------------------------
// K12: FUSED region-projection + channel softmax + rowsum partials.
// Block = (64-token chunk n0, batch b); 512 thr / 8 waves.
// P[b,p,n0+j] = softmax_p( Wr[p,:]·x[b,:,n] + br[p] ), all 1024 p in-block.
// xt tile (64n x 256k, 32 KB) resident in LDS; Wr streamed in 8 chunks of
// 128 p-rows (BK=64). Logits kept packed-bf16 in registers (st, all static
// indices). Softmax: chunk max -> lane/wave reduce -> M; register re-exp ->
// S; normalize -> LDS restage -> coalesced P stores + fused sPpart rowsums.
// ---------------------------------------------------------------------------
__global__ __launch_bounds__(512) void k12_proj_sm(const ushort_t* __restrict__ Wrb,
                                                   const ushort_t* __restrict__ xt,
                                                   const float* __restrict__ br,
                                                   ushort_t* __restrict__ P,
                                                   float* __restrict__ sPpart) {
  __shared__ __align__(16) ushort_t xts[64 * 256];  // 32 KB, swizzled [n][k]
  __shared__ __align__(16) ushort_t As[128 * 66];   // 16.5 KB (GEMM stride 64 / stage stride 66)
  __shared__ float red[8][64];
  __shared__ float Mrun[64], Sinv[64];
  const int tid = threadIdx.x;
  const int nblk = blockIdx.x, b = blockIdx.y;
  const int n0 = nblk * 64;
  const int l = tid & 63, w = tid >> 6;
  const int col = l & 15, lg = l >> 4;
  const int kq = lg * 8;
  const int swz = (col & 7) << 3;

  // stage xts: [n][k ^ ((n&7)<<3)]
#pragma unroll
  for (int j = 0; j < 4; j++) {
    int unit = tid + j * 512;
    int n = unit >> 5, k8 = (unit & 31) * 8;
    ushort8_t v = *(const ushort8_t*)(xt + ((size_t)b * NN + n0 + n) * NC + k8);
    *(ushort8_t*)&xts[n * 256 + (k8 ^ ((n & 7) << 3))] = v;
  }

  uint32_t st[8][4][2];  // packed bf16 logits: [chunk][fn][rg-pair]
#pragma unroll
  for (int pc = 0; pc < 8; pc++) {
    f32x4 acc[4] = {};
#pragma unroll
    for (int it = 0; it < 4; it++) {
#pragma unroll
      for (int i = 0; i < 2; i++) {
        const int rbase = i * 64 + w * 8;
        const int row = rbase + (l >> 3);
        const int sc = ((l & 7) ^ (row & 7)) << 3;
        glds16(Wrb + (size_t)(pc * 128 + row) * NC + it * 64 + sc, As + rbase * 64);
      }
      __syncthreads();
#pragma unroll
      for (int ks = 0; ks < 2; ks++) {
        const int cc = ks * 32 + kq;
        bf16x8 af = *(const bf16x8*)&As[(w * 16 + col) * 64 + (cc ^ swz)];
#pragma unroll
        for (int fn = 0; fn < 4; fn++) {
          bf16x8 bf = *(const bf16x8*)&xts[(fn * 16 + col) * 256 + it * 64 + (cc ^ swz)];
          acc[fn] = mfma16(af, bf, acc[fn]);
        }
      }
      __syncthreads();
    }
    // bias add, pack to registers, chunk max
    const float4 brv = *(const float4*)(br + pc * 128 + w * 16 + lg * 4);
    float mx[4];
#pragma unroll
    for (int fn = 0; fn < 4; fn++) {
      float v0 = acc[fn][0] + brv.x;
      float v1 = acc[fn][1] + brv.y;
      float v2 = acc[fn][2] + brv.z;
      float v3 = acc[fn][3] + brv.w;
      st[pc][fn][0] = ((uint32_t)f2b(v1) << 16) | f2b(v0);
      st[pc][fn][1] = ((uint32_t)f2b(v3) << 16) | f2b(v2);
      mx[fn] = fmaxf(fmaxf(v0, v1), fmaxf(v2, v3));
    }
#pragma unroll
    for (int fn = 0; fn < 4; fn++) {
      mx[fn] = fmaxf(mx[fn], __shfl_xor(mx[fn], 16, 64));
      mx[fn] = fmaxf(mx[fn], __shfl_xor(mx[fn], 32, 64));
    }
    if (lg == 0) {
#pragma unroll
      for (int fn = 0; fn < 4; fn++) red[w][fn * 16 + col] = mx[fn];
    }
    __syncthreads();
    if (tid < 64) {
      float m8 = red[0][tid];
#pragma unroll
      for (int g = 1; g < 8; g++) m8 = fmaxf(m8, red[g][tid]);
      Mrun[tid] = (pc == 0) ? m8 : fmaxf(Mrun[tid], m8);
    }
    // no barrier needed: Mrun only read after all chunks; red rewritten
    // only after the next chunk's K-step barriers.
  }
  __syncthreads();
  // pass 2a: exp in-register, accumulate S
  float Mn[4], ssum[4];
#pragma unroll
  for (int fn = 0; fn < 4; fn++) { Mn[fn] = Mrun[fn * 16 + col]; ssum[fn] = 0.f; }
#pragma unroll
  for (int pc = 0; pc < 8; pc++)
#pragma unroll
    for (int fn = 0; fn < 4; fn++)
#pragma unroll
      for (int j = 0; j < 2; j++) {
        uint32_t u = st[pc][fn][j];
        float e0 = __expf(b2f((ushort_t)(u & 0xFFFFu)) - Mn[fn]);
        float e1 = __expf(b2f((ushort_t)(u >> 16)) - Mn[fn]);
        st[pc][fn][j] = ((uint32_t)f2b(e1) << 16) | f2b(e0);
        ssum[fn] += e0 + e1;
      }
#pragma unroll
  for (int fn = 0; fn < 4; fn++) {
    ssum[fn] += __shfl_xor(ssum[fn], 16, 64);
    ssum[fn] += __shfl_xor(ssum[fn], 32, 64);
  }
  if (lg == 0) {
#pragma unroll
    for (int fn = 0; fn < 4; fn++) red[w][fn * 16 + col] = ssum[fn];
  }
  __syncthreads();
  if (tid < 64) {
    float S = 0.f;
#pragma unroll
    for (int g = 0; g < 8; g++) S += red[g][tid];
    Sinv[tid] = 1.f / S;
  }
  __syncthreads();
  float sv[4];
#pragma unroll
  for (int fn = 0; fn < 4; fn++) sv[fn] = Sinv[fn * 16 + col];
  // pass 2b: normalize, restage, rowsum, coalesced P stores
#pragma unroll
  for (int pc = 0; pc < 8; pc++) {
    float rsum[4] = {0.f, 0.f, 0.f, 0.f};
#pragma unroll
    for (int fn = 0; fn < 4; fn++)
#pragma unroll
      for (int j = 0; j < 2; j++) {
        uint32_t u = st[pc][fn][j];
        float p0 = b2f((ushort_t)(u & 0xFFFFu)) * sv[fn];
        float p1 = b2f((ushort_t)(u >> 16)) * sv[fn];
        const int rl = w * 16 + lg * 4 + j * 2;
        As[rl * 66 + fn * 16 + col] = f2b(p0);
        As[(rl + 1) * 66 + fn * 16 + col] = f2b(p1);
        rsum[j * 2] += p0;
        rsum[j * 2 + 1] += p1;
      }
#pragma unroll
    for (int rg = 0; rg < 4; rg++) {
      rsum[rg] += __shfl_xor(rsum[rg], 1, 64);
      rsum[rg] += __shfl_xor(rsum[rg], 2, 64);
      rsum[rg] += __shfl_xor(rsum[rg], 4, 64);
      rsum[rg] += __shfl_xor(rsum[rg], 8, 64);
    }
    if (col == 0) {
      const int pbase = pc * 128 + w * 16 + lg * 4;
      *(float4*)&sPpart[((size_t)nblk * NB + b) * NP + pbase] =
          make_float4(rsum[0], rsum[1], rsum[2], rsum[3]);
    }
    __syncthreads();
    const int row = tid >> 2, q = tid & 3;
    const ushort_t* s = &As[row * 66 + q * 16];
    ushort_t* dst = P + ((size_t)b * NP + pc * 128 + row) * NN + n0 + q * 16;
    *(ushort8_t*)(dst) = *(const ushort8_t*)(s);
    *(ushort8_t*)(dst + 8) = *(const ushort8_t*)(s + 8);
    __syncthreads();
  }
}

// K2r: sP[b,p] = sum over 64 n-blocks
__global__ __launch_bounds__(256) void k2r_reduce(const float* __restrict__ sPpart,
                                                  float* __restrict__ sP) {
  int idx = blockIdx.x * 256 + threadIdx.x;
  float s = 0.f;
#pragma unroll 8
  for (int bx = 0; bx < 64; bx++) s += sPpart[(size_t)bx * (NB * NP) + idx];
  sP[idx] = s;
}

// ---------------------------------------------------------------------------
// K3: XRbT[b][p][c] = f2b( sum_n xb[b,c,n]·P[b,p,n] )  (transposed bf16 out)
// Full K=4096, grid 256, double-buffered BK=64 pipeline.
// ---------------------------------------------------------------------------
__global__ __launch_bounds__(256) void k3_pool(const ushort_t* __restrict__ xb,
                                               const ushort_t* __restrict__ P,
                                               ushort_t* __restrict__ XRbT) {
  __shared__ __align__(16) ushort_t SH[4 * 8192];  // 64 KB dbuf
  const int tid = threadIdx.x;
  const int ord = blockIdx.x;  // 256 blocks
  const int L = (ord & 7) * 32 + (ord >> 3);
  const int m0 = (L & 1) * 128;         // c
  const int n0 = ((L >> 1) & 7) * 128;  // p
  const int b = L >> 4;
  const int l = tid & 63, w = tid >> 6;
  const int fr = l & 15, kq = (l >> 4) * 8;
  const int rr = l >> 3;
  const int sc = ((l & 7) ^ rr) << 3;
  const int swz = (fr & 7) << 3;
  const int wm = (w >> 1) * 64, wn = (w & 1) * 64;
  const ushort_t* Asrc = xb + ((size_t)b * NC + m0) * NN;
  const ushort_t* Bsrc = P + ((size_t)b * NP + n0) * NN;
  f32x4 acc[4][4] = {};

  auto STAGE = [&](int bi, size_t k0) {
    ushort_t* Ad = SH + bi * 8192;
    ushort_t* Bd = SH + 16384 + bi * 8192;
#pragma unroll
    for (int i = 0; i < 4; i++) {
      const int row = i * 32 + w * 8 + rr;
      glds16(Asrc + (size_t)row * NN + k0 + sc, Ad + (i * 32 + w * 8) * 64);
      glds16(Bsrc + (size_t)row * NN + k0 + sc, Bd + (i * 32 + w * 8) * 64);
    }
  };

  STAGE(0, 0);
  __syncthreads();
  int cur = 0;
#pragma unroll 1
  for (int it = 0; it < 64; it++) {
    if (it + 1 < 64) STAGE(cur ^ 1, (size_t)(it + 1) * 64);
    const ushort_t* Ar = SH + cur * 8192;
    const ushort_t* Br = SH + 16384 + cur * 8192;
#pragma unroll
    for (int ks = 0; ks < 2; ks++) {
      const int col = ks * 32 + kq;
      bf16x8 af[4], bf[4];
#pragma unroll
      for (int f = 0; f < 4; f++) {
        af[f] = *(const bf16x8*)&Ar[(wm + f * 16 + fr) * 64 + (col ^ swz)];
        bf[f] = *(const bf16x8*)&Br[(wn + f * 16 + fr) * 64 + (col ^ swz)];
      }
#pragma unroll
      for (int fm = 0; fm < 4; fm++)
#pragma unroll
        for (int fn = 0; fn < 4; fn++)
          acc[fm][fn] = mfma16(af[fm], bf[fn], acc[fm][fn]);
    }
    __syncthreads();
    cur ^= 1;
  }
  // transposed epilogue: stage[p_local][c_local] stride 136, 2 passes
  const int colc = l & 15, rb = (l >> 4) * 4;
#pragma unroll
  for (int pp = 0; pp < 2; pp++) {
    if ((w & 1) == pp) {
#pragma unroll
      for (int fm = 0; fm < 4; fm++)
#pragma unroll
        for (int rg = 0; rg < 4; rg++) {
          const int cl = wm + fm * 16 + rb + rg;  // 0..127
#pragma unroll
          for (int fn = 0; fn < 4; fn++) {
            const int pl = fn * 16 + colc;  // 0..63
            SH[pl * 136 + cl] = f2b(acc[fm][fn][rg]);
          }
        }
    }
    __syncthreads();
    const int prow = tid >> 2, cch = (tid & 3) * 32;
    ushort_t* dst = XRbT + ((size_t)b * NP + n0 + pp * 64 + prow) * NC + m0 + cch;
    const ushort_t* s = &SH[prow * 136 + cch];
#pragma unroll
    for (int j = 0; j < 4; j++)
      *(ushort8_t*)(dst + j * 8) = *(const ushort8_t*)(s + j * 8);
    __syncthreads();
  }
}

// ---------------------------------------------------------------------------
// K4a: QKVRb[b][o][p] = f2b( Wqkvb[o,:]·XRbT[b,p,:] + bqkv[o]·sP[b,p] )
// ---------------------------------------------------------------------------
__global__ __launch_bounds__(256) void k4a_qkvr(const ushort_t* __restrict__ Wqkvb,
                                                const ushort_t* __restrict__ XRbT,
                                                const float* __restrict__ bqkv,
                                                const float* __restrict__ sP,
                                                ushort_t* __restrict__ QKVRb) {
  __shared__ __align__(16) ushort_t SH[2 * 8192];  // 32 KB single-buf
  const int tid = threadIdx.x;
  const int ord = blockIdx.x;
  const int L = (ord & 7) * 96 + (ord >> 3);
  const int m0 = (L % 6) * 128;
  const int rest = L / 6;
  const int n0 = (rest & 7) * 128;
  const int b = rest >> 3;
  const int lane = tid & 63, w = tid >> 6;
  const int wm = (w >> 1) * 64, wn = (w & 1) * 64;
  f32x4 acc[4][4] = {};
  gemm_core_sb<4>(Wqkvb + (size_t)m0 * NC, NC,
                  XRbT + ((size_t)b * NP + n0) * NC, NC, SH, acc, tid);
  const int col = lane & 15, rb = (lane >> 4) * 4;
  float spv[4];
#pragma unroll
  for (int fn = 0; fn < 4; fn++) spv[fn] = sP[(size_t)b * NP + n0 + wn + fn * 16 + col];
#pragma unroll
  for (int fm = 0; fm < 4; fm++)
#pragma unroll
    for (int rg = 0; rg < 4; rg++) {
      int row = m0 + wm + fm * 16 + rb + rg;
      float bq = bqkv[row];
#pragma unroll
      for (int fn = 0; fn < 4; fn++) {
        int cc = n0 + wn + fn * 16 + col;
        QKVRb[((size_t)b * NO + row) * NP + cc] = f2b(acc[fm][fn][rg] + bq * spv[fn]);
      }
    }
}

// ---------------------------------------------------------------------------
// K4b: per-(b,h) tiny attention + Wout fold -> Tmb (bf16)
// ---------------------------------------------------------------------------
__global__ __launch_bounds__(256) void k4b_attn(const ushort_t* __restrict__ QKVRb,
                                                const float* __restrict__ Wout,
                                                ushort_t* __restrict__ Tmb) {
  const int b = blockIdx.x >> 3, h = blockIdx.x & 7;
  const int tid = threadIdx.x;
  __shared__ float qf[96][64];       // q(0:32) k(32:64) v(64:96)
  __shared__ float attn_sT[64][65];  // [k][q]
  __shared__ float vals_s[32][64];
#pragma unroll
  for (int i = 0; i < 3; i++) {
    int u = i * 256 + tid;
    int rw = u >> 3, jc = (u & 7) * 8;
    int p0 = h * 128 + ((rw < 32) ? 0 : 64);
    ushort8_t v = *(const ushort8_t*)(QKVRb + ((size_t)b * NO + h * 96 + rw) * NP + p0 + jc);
#pragma unroll
    for (int j = 0; j < 8; j++) qf[rw][jc + j] = b2f(v[j]);
  }
  __syncthreads();
  const int lj = tid & 63;
  const int rq = tid >> 6;
  float kcol[32];
#pragma unroll
  for (int dd = 0; dd < 32; dd++) kcol[dd] = qf[32 + dd][lj];
  const float isc = 0.17677669529663687f;
#pragma unroll
  for (int r = 0; r < 16; r++) {
    int qi = r * 4 + rq;
    float a = 0.f;
#pragma unroll
    for (int dd = 0; dd < 32; dd++) a += qf[dd][qi] * kcol[dd];
    attn_sT[lj][qi] = a * isc;
  }
  __syncthreads();
  if (tid < 64) {
    float m = -3e38f;
    for (int k = 0; k < 64; k++) m = fmaxf(m, attn_sT[k][tid]);
    float s = 0.f;
    for (int k = 0; k < 64; k++) {
      float e = __expf(attn_sT[k][tid] - m);
      attn_sT[k][tid] = e;
      s += e;
    }
    float inv = 1.f / s;
    for (int k = 0; k < 64; k++) attn_sT[k][tid] *= inv;
  }
  __syncthreads();
  float acol[64];
#pragma unroll
  for (int k = 0; k < 64; k++) acol[k] = attn_sT[k][lj];
#pragma unroll
  for (int r = 0; r < 8; r++) {
    int dd = r * 4 + rq;
    float a = 0.f;
#pragma unroll
    for (int k = 0; k < 64; k++) a += qf[64 + dd][k] * acol[k];
    vals_s[dd][lj] = a;
  }
  __syncthreads();
  float vcol[32];
#pragma unroll
  for (int dd = 0; dd < 32; dd++) vcol[dd] = vals_s[dd][lj];
  for (int r = 0; r < 64; r++) {
    int c = r * 4 + rq;
    const float4* wp = (const float4*)(Wout + (size_t)c * NC + h * 32);
    float a = 0.f;
#pragma unroll
    for (int t = 0; t < 8; t++) {
      float4 w = wp[t];
      a += w.x * vcol[t * 4] + w.y * vcol[t * 4 + 1] + w.z * vcol[t * 4 + 2] +
           w.w * vcol[t * 4 + 3];
    }
    Tmb[((size_t)b * NC + c) * NT + h * 64 + lj] = f2b(a);
  }
}

// ---------------------------------------------------------------------------
// K5: out = x + alpha*(Tmb·Pq + bout). Pipelined: A glds dbuf; B reg-staged
// (load-early / ds_write-late) into pad-72 dbuf LDS tile.
// ---------------------------------------------------------------------------
__global__ __launch_bounds__(256) void k5_out(const float* __restrict__ x,
                                              const ushort_t* __restrict__ P,
                                              const ushort_t* __restrict__ Tmb,
                                              const float* __restrict__ bout,
                                              const float* __restrict__ alpha,
                                              float* __restrict__ out) {
  __shared__ __align__(16) ushort_t Ash[2 * 8192];  // 32 KB
  __shared__ __align__(16) ushort_t Bsh[2 * 9216];  // 36 KB (128 rows x 72)
  const int tid = threadIdx.x;
  const int ord = blockIdx.x;
  const int L = (ord & 7) * 128 + (ord >> 3);
  const int m0 = (L & 1) * 128;
  const int n0 = ((L >> 1) & 31) * 128;
  const int b = L >> 6;
  const int lane = tid & 63, w = tid >> 6;
  const int wm = (w >> 1) * 64, wn = (w & 1) * 64;
  const int fr = lane & 15, kq = (lane >> 4) * 8;
  const int rr = lane >> 3, sc = ((lane & 7) ^ rr) << 3;
  const int swz = (fr & 7) << 3;
  const ushort_t* Asrc = Tmb + ((size_t)b * NC + m0) * NT;
  const int kg = tid >> 5, ng = (tid & 31) * 4;  // B stage: 8 k-rows x 4 n
  f32x4 acc[4][4] = {};
  ushort4_t bv[8];

  auto A_STAGE = [&](int bi, int k0) {
    ushort_t* Ad = Ash + bi * 8192;
#pragma unroll
    for (int i = 0; i < 4; i++) {
      const int row = i * 32 + w * 8 + rr;
      glds16(Asrc + (size_t)row * NT + k0 + sc, Ad + (i * 32 + w * 8) * 64);
    }
  };
  auto B_LOAD = [&](int k0) {
#pragma unroll
    for (int i = 0; i < 8; i++) {
      int hj = k0 + kg * 8 + i;
      int prow = ((hj >> 6) << 7) + (hj & 63);
      bv[i] = *(const ushort4_t*)(P + ((size_t)b * NP + prow) * NN + n0 + ng);
    }
  };
  auto B_WRITE = [&](int bi) {
#pragma unroll
    for (int jj = 0; jj < 4; jj++) {
      ushort8_t pk;
#pragma unroll
      for (int i = 0; i < 8; i++) pk[i] = bv[i][jj];
      *(ushort8_t*)&Bsh[bi * 9216 + (ng + jj) * 72 + kg * 8] = pk;
    }
  };

  A_STAGE(0, 0);
  B_LOAD(0);
  B_WRITE(0);
  __syncthreads();
  int cur = 0;
#pragma unroll 1
  for (int it = 0; it < 8; it++) {
    if (it + 1 < 8) {
      A_STAGE(cur ^ 1, (it + 1) * 64);
      B_LOAD((it + 1) * 64);
    }
    const ushort_t* Ar = Ash + cur * 8192;
    const ushort_t* Br = Bsh + cur * 9216;
#pragma unroll
    for (int ks = 0; ks < 2; ks++) {
      const int col = ks * 32 + kq;
      bf16x8 af[4], bf[4];
#pragma unroll
      for (int f = 0; f < 4; f++) {
        af[f] = *(const bf16x8*)&Ar[(wm + f * 16 + fr) * 64 + (col ^ swz)];
        bf[f] = *(const bf16x8*)&Br[(wn + f * 16 + fr) * 72 + col];
      }
#pragma unroll
      for (int fm = 0; fm < 4; fm++)
#pragma unroll
        for (int fn = 0; fn < 4; fn++)
          acc[fm][fn] = mfma16(af[fm], bf[fn], acc[fm][fn]);
    }
    if (it + 1 < 8) B_WRITE(cur ^ 1);
    __syncthreads();
    cur ^= 1;
  }
  const float al = alpha[0];
  const int col = lane & 15, rb = (lane >> 4) * 4;
#pragma unroll
  for (int fm = 0; fm < 4; fm++)
#pragma unroll
    for (int rg = 0; rg < 4; rg++) {
      int row = m0 + wm + fm * 16 + rb + rg;
      float bias = bout[row];
#pragma unroll
      for (int fn = 0; fn < 4; fn++) {
        int cc = n0 + wn + fn * 16 + col;
        size_t idx = ((size_t)b * NC + row) * NN + cc;
        out[idx] = x[idx] + al * (acc[fm][fn][rg] + bias);
      }
    }
}

// ---------------------------------------------------------------------------
extern "C" void kernel_launch(void* const* d_in, const int* in_sizes, int n_in,
                              void* d_out, int out_size, void* d_ws, size_t ws_size,
                              hipStream_t stream) {
  const float* x = (const float*)d_in[0];
  const float* Wqkv = (const float*)d_in[1];
  const float* bqkv = (const float*)d_in[2];
  const float* Wr = (const float*)d_in[3];
  const float* br = (const float*)d_in[4];
  const float* Wout = (const float*)d_in[5];
  const float* bout = (const float*)d_in[6];
  const float* alpha = (const float*)d_in[7];
  float* out = (float*)d_out;

  char* ws = (char*)d_ws;
  ushort_t* P = (ushort_t*)ws;                    // [0, 134217728)
  ushort_t* xb = (ushort_t*)(ws + 134217728);     // 33.5MB (dead after k3)
  ushort_t* QKVRb = (ushort_t*)(ws + 134217728);  //   aliases xb: 25.2MB (k4a+)
  ushort_t* xt = (ushort_t*)(ws + 167772160);     // 33.5MB (dead after k12)
  ushort_t* XRbT = (ushort_t*)(ws + 167772160);   //   aliases xt: 8.4MB (k3+)
  ushort_t* Wrb = (ushort_t*)(ws + 201326592);    // 0.5MB
  float* sPpart = (float*)(ws + 201850880);       // 4.2MB (dead after k2r)
  ushort_t* Wqkvb = (ushort_t*)(ws + 201850880);  //   aliases sPpart: 0.4MB
  float* sP = (float*)(ws + 206045184);           // 64KB
  ushort_t* Tmb = (ushort_t*)(ws + 206110720);    // 4.2MB -> end 210305024

  k0_cvt<<<dim3(64, 4, 16), 256, 0, stream>>>(x, xb, xt);
  cvt_f2b_k<<<256, 256, 0, stream>>>(Wr, Wrb);
  k12_proj_sm<<<dim3(64, 16), 512, 0, stream>>>(Wrb, xt, br, P, sPpart);
  k2r_reduce<<<64, 256, 0, stream>>>(sPpart, sP);
  cvt_f2b_k<<<192, 256, 0, stream>>>(Wqkv, Wqkvb);  // after k2r (aliases sPpart)
  k3_pool<<<256, 256, 0, stream>>>(xb, P, XRbT);    // writes into xt region (xt dead)
  k4a_qkvr<<<768, 256, 0, stream>>>(Wqkvb, XRbT, bqkv, sP, QKVRb);
  k4b_attn<<<128, 256, 0, stream>>>(QKVRb, Wout, Tmb);
  k5_out<<<1024, 256, 0, stream>>>(x, P, Tmb, bout, alpha, out);
}

// Round 9
// 339.415 us; speedup vs baseline: 1.1286x; 1.1286x over previous
//
#include <hip/hip_runtime.h>
#include <cstdint>

typedef unsigned short ushort_t;
typedef __attribute__((ext_vector_type(4))) unsigned short ushort4_t;
typedef __attribute__((ext_vector_type(8))) unsigned short ushort8_t;
typedef __attribute__((ext_vector_type(8))) __bf16 bf16x8;
typedef __attribute__((ext_vector_type(4))) float f32x4;

constexpr int NB = 16;    // batch
constexpr int NC = 256;   // channels C (== E)
constexpr int NN = 4096;  // tokens N = H*W
constexpr int NP = 1024;  // region-proj channels = 2*R*heads
constexpr int NT = 512;   // heads * R (Rq columns of T)
constexpr int NO = 768;   // 3*E rows of Wqkv

static __device__ __forceinline__ ushort_t f2b(float f) {
  uint32_t u = __builtin_bit_cast(uint32_t, f);
  u += 0x7FFFu + ((u >> 16) & 1u);
  return (ushort_t)(u >> 16);
}
static __device__ __forceinline__ float b2f(ushort_t h) {
  return __builtin_bit_cast(float, (uint32_t)h << 16);
}
static __device__ __forceinline__ f32x4 mfma16(bf16x8 a, bf16x8 b, f32x4 c) {
  return __builtin_amdgcn_mfma_f32_16x16x32_bf16(a, b, c, 0, 0, 0);
}
typedef __attribute__((address_space(1))) const unsigned int guint;
typedef __attribute__((address_space(3))) unsigned int luint;
static __device__ __forceinline__ void glds16(const void* g, void* l) {
  __builtin_amdgcn_global_load_lds((guint*)g, (luint*)l, 16, 0, 0);
}

// ---------------------------------------------------------------------------
// Single-buffer 128x128 GEMM core (m97-style): BK=64, XOR-swizzled LDS,
// 2 barriers per K-step. Uses SH[0,16384) (As at 0, Bs at 8192 elems).
// ---------------------------------------------------------------------------
template <int KITERS>
__device__ __forceinline__ void gemm_core_sb(const ushort_t* __restrict__ Asrc, size_t lda,
                                             const ushort_t* __restrict__ Bsrc, size_t ldb,
                                             ushort_t* SH, f32x4 (&acc)[4][4], int tid) {
  const int l = tid & 63, w = tid >> 6;
  const int fr = l & 15, kq = (l >> 4) * 8;
  const int rr = l >> 3;
  const int sc = ((l & 7) ^ rr) << 3;
  const int swz = (fr & 7) << 3;
  const int wm = (w >> 1) * 64, wn = (w & 1) * 64;
  ushort_t* As = SH;
  ushort_t* Bs = SH + 8192;
#pragma unroll 1
  for (int it = 0; it < KITERS; it++) {
    const size_t k0 = (size_t)it * 64;
#pragma unroll
    for (int i = 0; i < 4; i++) {
      const int row = i * 32 + w * 8 + rr;
      glds16(Asrc + (size_t)row * lda + k0 + sc, As + (i * 32 + w * 8) * 64);
      glds16(Bsrc + (size_t)row * ldb + k0 + sc, Bs + (i * 32 + w * 8) * 64);
    }
    __syncthreads();
#pragma unroll
    for (int ks = 0; ks < 2; ks++) {
      const int col = ks * 32 + kq;
      bf16x8 af[4], bf[4];
#pragma unroll
      for (int f = 0; f < 4; f++) {
        af[f] = *(const bf16x8*)&As[(wm + f * 16 + fr) * 64 + (col ^ swz)];
        bf[f] = *(const bf16x8*)&Bs[(wn + f * 16 + fr) * 64 + (col ^ swz)];
      }
#pragma unroll
      for (int fm = 0; fm < 4; fm++)
#pragma unroll
        for (int fn = 0; fn < 4; fn++)
          acc[fm][fn] = mfma16(af[fm], bf[fn], acc[fm][fn]);
    }
    __syncthreads();
  }
}

// ---------------------------------------------------------------------------
// K0: x (f32 [b][c][n]) -> xb (bf16 [b][c][n]) and xt (bf16 [b][n][c])
// ---------------------------------------------------------------------------
__global__ __launch_bounds__(256) void k0_cvt(const float* __restrict__ x,
                                              ushort_t* __restrict__ xb,
                                              ushort_t* __restrict__ xt) {
  __shared__ ushort_t tr[64][88];
  const int tid = threadIdx.x;
  const int n0 = blockIdx.x * 64, c0 = blockIdx.y * 64, b = blockIdx.z;
  const int cr = (tid >> 4) * 4;
  const int nc4 = (tid & 15) * 4;
#pragma unroll
  for (int i = 0; i < 4; i++) {
    size_t idx = ((size_t)b * NC + c0 + cr + i) * NN + n0 + nc4;
    float4 v = *(const float4*)(x + idx);
    ushort4_t o;
    o[0] = f2b(v.x); o[1] = f2b(v.y); o[2] = f2b(v.z); o[3] = f2b(v.w);
    *(ushort4_t*)(xb + idx) = o;
    tr[nc4 + 0][cr + i] = o[0];
    tr[nc4 + 1][cr + i] = o[1];
    tr[nc4 + 2][cr + i] = o[2];
    tr[nc4 + 3][cr + i] = o[3];
  }
  __syncthreads();
  const int nr = tid >> 2, cc0 = (tid & 3) * 16;
  size_t odx = ((size_t)b * NN + n0 + nr) * NC + c0 + cc0;
  *(ushort8_t*)(xt + odx) = *(const ushort8_t*)&tr[nr][cc0];
  *(ushort8_t*)(xt + odx + 8) = *(const ushort8_t*)&tr[nr][cc0 + 8];
}

// generic f32 -> bf16 (count multiple of 1024)
__global__ __launch_bounds__(256) void cvt_f2b_k(const float* __restrict__ src,
                                                 ushort_t* __restrict__ dst) {
  int i = (blockIdx.x * 256 + threadIdx.x) * 4;
  float4 v = *(const float4*)(src + i);
  ushort4_t o;
  o[0] = f2b(v.x); o[1] = f2b(v.y); o[2] = f2b(v.z); o[3] = f2b(v.w);
  *(ushort4_t*)(dst + i) = o;
}

// ---------------------------------------------------------------------------
// K1: P[b,p,n] = Wrb[p,:]·xt[b,n,:] + br[p]   (bf16 out, pre-softmax)
// 128x128, single-buffer gemm_core_sb (R4's 71us core) + LDS-restaged
// coalesced epilogue (stride 136 -> 16B/lane P stores).
// ---------------------------------------------------------------------------
__global__ __launch_bounds__(256) void k1_proj(const ushort_t* __restrict__ Wrb,
                                               const ushort_t* __restrict__ xt,
                                               const float* __restrict__ br,
                                               ushort_t* __restrict__ P) {
  __shared__ __align__(16) ushort_t SH[17408];  // 34.8 KB (gemm 32KB / restage 128x136)
  const int tid = threadIdx.x;
  const int ord = blockIdx.x;
  const int L = (ord & 7) * 512 + (ord >> 3);
  const int m0 = (L & 7) * 128;
  const int n0 = ((L >> 3) & 31) * 128;
  const int b = L >> 8;
  const int lane = tid & 63, w = tid >> 6;
  const int wm = (w >> 1) * 64, wn = (w & 1) * 64;
  f32x4 acc[4][4] = {};
  gemm_core_sb<4>(Wrb + (size_t)m0 * NC, NC,
                  xt + ((size_t)b * NN + n0) * NC, NC, SH, acc, tid);
  const int colc = lane & 15, rb = (lane >> 4) * 4;
#pragma unroll
  for (int fm = 0; fm < 4; fm++)
#pragma unroll
    for (int rg = 0; rg < 4; rg++) {
      const int row = wm + fm * 16 + rb + rg;  // 0..127
      const float bias = br[m0 + row];
#pragma unroll
      for (int fn = 0; fn < 4; fn++)
        SH[row * 136 + wn + fn * 16 + colc] = f2b(acc[fm][fn][rg] + bias);
    }
  __syncthreads();
  const int orow = tid >> 1, half = tid & 1;
  const ushort_t* s = &SH[orow * 136 + half * 64];
  ushort_t* dst = P + ((size_t)b * NP + m0 + orow) * NN + n0 + half * 64;
#pragma unroll
  for (int j = 0; j < 8; j++)
    *(ushort8_t*)(dst + j * 8) = *(const ushort8_t*)(s + j * 8);
}

// ---------------------------------------------------------------------------
// K2: softmax over p (1024) per (b,n) column, in-place; rowsum partials.
// 512 thr; rows held in registers (single global read).
// ---------------------------------------------------------------------------
__global__ __launch_bounds__(512) void k2_softmax(ushort_t* __restrict__ P,
                                                  float* __restrict__ sPpart) {
  __shared__ float red[64][64];
  __shared__ float Mf[64], If[64];
  const int tid = threadIdx.x;
  const int n0 = blockIdx.x * 64, b = blockIdx.y;
  const int cg = tid & 7, pg = tid >> 3;
  ushort_t* base = P + (size_t)b * NP * NN + n0 + cg * 8;

  ushort8_t v[16];
  float m[8];
#pragma unroll
  for (int j = 0; j < 8; j++) m[j] = -3.0e38f;
#pragma unroll
  for (int r = 0; r < 16; r++) {
    v[r] = *(const ushort8_t*)(base + (size_t)(pg * 16 + r) * NN);
#pragma unroll
    for (int j = 0; j < 8; j++) m[j] = fmaxf(m[j], b2f(v[r][j]));
  }
#pragma unroll
  for (int j = 0; j < 8; j++) red[pg][cg * 8 + j] = m[j];
  __syncthreads();
  if (tid < 64) {
    float M = -3.0e38f;
    for (int g = 0; g < 64; g++) M = fmaxf(M, red[g][tid]);
    Mf[tid] = M;
  }
  __syncthreads();
  float mj[8], s[8];
#pragma unroll
  for (int j = 0; j < 8; j++) { mj[j] = Mf[cg * 8 + j]; s[j] = 0.f; }
#pragma unroll
  for (int r = 0; r < 16; r++)
#pragma unroll
    for (int j = 0; j < 8; j++) s[j] += __expf(b2f(v[r][j]) - mj[j]);
#pragma unroll
  for (int j = 0; j < 8; j++) red[pg][cg * 8 + j] = s[j];
  __syncthreads();
  if (tid < 64) {
    float S = 0.f;
    for (int g = 0; g < 64; g++) S += red[g][tid];
    If[tid] = 1.f / S;
  }
  __syncthreads();
  float ij[8];
#pragma unroll
  for (int j = 0; j < 8; j++) ij[j] = If[cg * 8 + j];
#pragma unroll
  for (int r = 0; r < 16; r++) {
    int p = pg * 16 + r;
    ushort8_t o;
    float rs = 0.f;
#pragma unroll
    for (int j = 0; j < 8; j++) {
      float e = __expf(b2f(v[r][j]) - mj[j]) * ij[j];
      o[j] = f2b(e);
      rs += e;
    }
    *(ushort8_t*)(base + (size_t)p * NN) = o;
    rs += __shfl_xor(rs, 1, 64);
    rs += __shfl_xor(rs, 2, 64);
    rs += __shfl_xor(rs, 4, 64);
    if (cg == 0) sPpart[((size_t)blockIdx.x * NB + b) * NP + p] = rs;
  }
}

// K2r: sP[b,p] = sum over 64 n-blocks
__global__ __launch_bounds__(256) void k2r_reduce(const float* __restrict__ sPpart,
                                                  float* __restrict__ sP) {
  int idx = blockIdx.x * 256 + threadIdx.x;
  float s = 0.f;
#pragma unroll 8
  for (int bx = 0; bx < 64; bx++) s += sPpart[(size_t)bx * (NB * NP) + idx];
  sP[idx] = s;
}

// ---------------------------------------------------------------------------
// K3: XRbT[b][p][c] = f2b( sum_n xb[b,c,n]·P[b,p,n] )  (transposed bf16 out)
// Full K=4096, grid 256, double-buffered BK=64 pipeline.
// ---------------------------------------------------------------------------
__global__ __launch_bounds__(256) void k3_pool(const ushort_t* __restrict__ xb,
                                               const ushort_t* __restrict__ P,
                                               ushort_t* __restrict__ XRbT) {
  __shared__ __align__(16) ushort_t SH[4 * 8192];  // 64 KB dbuf
  const int tid = threadIdx.x;
  const int ord = blockIdx.x;  // 256 blocks
  const int L = (ord & 7) * 32 + (ord >> 3);
  const int m0 = (L & 1) * 128;         // c
  const int n0 = ((L >> 1) & 7) * 128;  // p
  const int b = L >> 4;
  const int l = tid & 63, w = tid >> 6;
  const int fr = l & 15, kq = (l >> 4) * 8;
  const int rr = l >> 3;
  const int sc = ((l & 7) ^ rr) << 3;
  const int swz = (fr & 7) << 3;
  const int wm = (w >> 1) * 64, wn = (w & 1) * 64;
  const ushort_t* Asrc = xb + ((size_t)b * NC + m0) * NN;
  const ushort_t* Bsrc = P + ((size_t)b * NP + n0) * NN;
  f32x4 acc[4][4] = {};

  auto STAGE = [&](int bi, size_t k0) {
    ushort_t* Ad = SH + bi * 8192;
    ushort_t* Bd = SH + 16384 + bi * 8192;
#pragma unroll
    for (int i = 0; i < 4; i++) {
      const int row = i * 32 + w * 8 + rr;
      glds16(Asrc + (size_t)row * NN + k0 + sc, Ad + (i * 32 + w * 8) * 64);
      glds16(Bsrc + (size_t)row * NN + k0 + sc, Bd + (i * 32 + w * 8) * 64);
    }
  };

  STAGE(0, 0);
  __syncthreads();
  int cur = 0;
#pragma unroll 1
  for (int it = 0; it < 64; it++) {
    if (it + 1 < 64) STAGE(cur ^ 1, (size_t)(it + 1) * 64);
    const ushort_t* Ar = SH + cur * 8192;
    const ushort_t* Br = SH + 16384 + cur * 8192;
#pragma unroll
    for (int ks = 0; ks < 2; ks++) {
      const int col = ks * 32 + kq;
      bf16x8 af[4], bf[4];
#pragma unroll
      for (int f = 0; f < 4; f++) {
        af[f] = *(const bf16x8*)&Ar[(wm + f * 16 + fr) * 64 + (col ^ swz)];
        bf[f] = *(const bf16x8*)&Br[(wn + f * 16 + fr) * 64 + (col ^ swz)];
      }
#pragma unroll
      for (int fm = 0; fm < 4; fm++)
#pragma unroll
        for (int fn = 0; fn < 4; fn++)
          acc[fm][fn] = mfma16(af[fm], bf[fn], acc[fm][fn]);
    }
    __syncthreads();
    cur ^= 1;
  }
  // transposed epilogue: stage[p_local][c_local] stride 136, 2 passes
  const int colc = l & 15, rb = (l >> 4) * 4;
#pragma unroll
  for (int pp = 0; pp < 2; pp++) {
    if ((w & 1) == pp) {
#pragma unroll
      for (int fm = 0; fm < 4; fm++)
#pragma unroll
        for (int rg = 0; rg < 4; rg++) {
          const int cl = wm + fm * 16 + rb + rg;  // 0..127
#pragma unroll
          for (int fn = 0; fn < 4; fn++) {
            const int pl = fn * 16 + colc;  // 0..63
            SH[pl * 136 + cl] = f2b(acc[fm][fn][rg]);
          }
        }
    }
    __syncthreads();
    const int prow = tid >> 2, cch = (tid & 3) * 32;
    ushort_t* dst = XRbT + ((size_t)b * NP + n0 + pp * 64 + prow) * NC + m0 + cch;
    const ushort_t* s = &SH[prow * 136 + cch];
#pragma unroll
    for (int j = 0; j < 4; j++)
      *(ushort8_t*)(dst + j * 8) = *(const ushort8_t*)(s + j * 8);
    __syncthreads();
  }
}

// ---------------------------------------------------------------------------
// K4a: QKVRb[b][o][p] = f2b( Wqkvb[o,:]·XRbT[b,p,:] + bqkv[o]·sP[b,p] )
// ---------------------------------------------------------------------------
__global__ __launch_bounds__(256) void k4a_qkvr(const ushort_t* __restrict__ Wqkvb,
                                                const ushort_t* __restrict__ XRbT,
                                                const float* __restrict__ bqkv,
                                                const float* __restrict__ sP,
                                                ushort_t* __restrict__ QKVRb) {
  __shared__ __align__(16) ushort_t SH[2 * 8192];  // 32 KB single-buf
  const int tid = threadIdx.x;
  const int ord = blockIdx.x;
  const int L = (ord & 7) * 96 + (ord >> 3);
  const int m0 = (L % 6) * 128;
  const int rest = L / 6;
  const int n0 = (rest & 7) * 128;
  const int b = rest >> 3;
  const int lane = tid & 63, w = tid >> 6;
  const int wm = (w >> 1) * 64, wn = (w & 1) * 64;
  f32x4 acc[4][4] = {};
  gemm_core_sb<4>(Wqkvb + (size_t)m0 * NC, NC,
                  XRbT + ((size_t)b * NP + n0) * NC, NC, SH, acc, tid);
  const int col = lane & 15, rb = (lane >> 4) * 4;
  float spv[4];
#pragma unroll
  for (int fn = 0; fn < 4; fn++) spv[fn] = sP[(size_t)b * NP + n0 + wn + fn * 16 + col];
#pragma unroll
  for (int fm = 0; fm < 4; fm++)
#pragma unroll
    for (int rg = 0; rg < 4; rg++) {
      int row = m0 + wm + fm * 16 + rb + rg;
      float bq = bqkv[row];
#pragma unroll
      for (int fn = 0; fn < 4; fn++) {
        int cc = n0 + wn + fn * 16 + col;
        QKVRb[((size_t)b * NO + row) * NP + cc] = f2b(acc[fm][fn][rg] + bq * spv[fn]);
      }
    }
}

// ---------------------------------------------------------------------------
// K4b: per-(b,h) tiny attention + Wout fold -> Tmb (bf16)
// ---------------------------------------------------------------------------
__global__ __launch_bounds__(256) void k4b_attn(const ushort_t* __restrict__ QKVRb,
                                                const float* __restrict__ Wout,
                                                ushort_t* __restrict__ Tmb) {
  const int b = blockIdx.x >> 3, h = blockIdx.x & 7;
  const int tid = threadIdx.x;
  __shared__ float qf[96][64];       // q(0:32) k(32:64) v(64:96)
  __shared__ float attn_sT[64][65];  // [k][q]
  __shared__ float vals_s[32][64];
#pragma unroll
  for (int i = 0; i < 3; i++) {
    int u = i * 256 + tid;
    int rw = u >> 3, jc = (u & 7) * 8;
    int p0 = h * 128 + ((rw < 32) ? 0 : 64);
    ushort8_t v = *(const ushort8_t*)(QKVRb + ((size_t)b * NO + h * 96 + rw) * NP + p0 + jc);
#pragma unroll
    for (int j = 0; j < 8; j++) qf[rw][jc + j] = b2f(v[j]);
  }
  __syncthreads();
  const int lj = tid & 63;
  const int rq = tid >> 6;
  float kcol[32];
#pragma unroll
  for (int dd = 0; dd < 32; dd++) kcol[dd] = qf[32 + dd][lj];
  const float isc = 0.17677669529663687f;
#pragma unroll
  for (int r = 0; r < 16; r++) {
    int qi = r * 4 + rq;
    float a = 0.f;
#pragma unroll
    for (int dd = 0; dd < 32; dd++) a += qf[dd][qi] * kcol[dd];
    attn_sT[lj][qi] = a * isc;
  }
  __syncthreads();
  if (tid < 64) {
    float m = -3e38f;
    for (int k = 0; k < 64; k++) m = fmaxf(m, attn_sT[k][tid]);
    float s = 0.f;
    for (int k = 0; k < 64; k++) {
      float e = __expf(attn_sT[k][tid] - m);
      attn_sT[k][tid] = e;
      s += e;
    }
    float inv = 1.f / s;
    for (int k = 0; k < 64; k++) attn_sT[k][tid] *= inv;
  }
  __syncthreads();
  float acol[64];
#pragma unroll
  for (int k = 0; k < 64; k++) acol[k] = attn_sT[k][lj];
#pragma unroll
  for (int r = 0; r < 8; r++) {
    int dd = r * 4 + rq;
    float a = 0.f;
#pragma unroll
    for (int k = 0; k < 64; k++) a += qf[64 + dd][k] * acol[k];
    vals_s[dd][lj] = a;
  }
  __syncthreads();
  float vcol[32];
#pragma unroll
  for (int dd = 0; dd < 32; dd++) vcol[dd] = vals_s[dd][lj];
  for (int r = 0; r < 64; r++) {
    int c = r * 4 + rq;
    const float4* wp = (const float4*)(Wout + (size_t)c * NC + h * 32);
    float a = 0.f;
#pragma unroll
    for (int t = 0; t < 8; t++) {
      float4 w = wp[t];
      a += w.x * vcol[t * 4] + w.y * vcol[t * 4 + 1] + w.z * vcol[t * 4 + 2] +
           w.w * vcol[t * 4 + 3];
    }
    Tmb[((size_t)b * NC + c) * NT + h * 64 + lj] = f2b(a);
  }
}

// ---------------------------------------------------------------------------
// K5: out = x + alpha*(Tmb·Pq + bout). Pipelined: A glds dbuf; B reg-staged
// (load-early / ds_write-late) into pad-72 dbuf LDS tile.
// ---------------------------------------------------------------------------
__global__ __launch_bounds__(256) void k5_out(const float* __restrict__ x,
                                              const ushort_t* __restrict__ P,
                                              const ushort_t* __restrict__ Tmb,
                                              const float* __restrict__ bout,
                                              const float* __restrict__ alpha,
                                              float* __restrict__ out) {
  __shared__ __align__(16) ushort_t Ash[2 * 8192];  // 32 KB
  __shared__ __align__(16) ushort_t Bsh[2 * 9216];  // 36 KB (128 rows x 72)
  const int tid = threadIdx.x;
  const int ord = blockIdx.x;
  const int L = (ord & 7) * 128 + (ord >> 3);
  const int m0 = (L & 1) * 128;
  const int n0 = ((L >> 1) & 31) * 128;
  const int b = L >> 6;
  const int lane = tid & 63, w = tid >> 6;
  const int wm = (w >> 1) * 64, wn = (w & 1) * 64;
  const int fr = lane & 15, kq = (lane >> 4) * 8;
  const int rr = lane >> 3, sc = ((lane & 7) ^ rr) << 3;
  const int swz = (fr & 7) << 3;
  const ushort_t* Asrc = Tmb + ((size_t)b * NC + m0) * NT;
  const int kg = tid >> 5, ng = (tid & 31) * 4;  // B stage: 8 k-rows x 4 n
  f32x4 acc[4][4] = {};
  ushort4_t bv[8];

  auto A_STAGE = [&](int bi, int k0) {
    ushort_t* Ad = Ash + bi * 8192;
#pragma unroll
    for (int i = 0; i < 4; i++) {
      const int row = i * 32 + w * 8 + rr;
      glds16(Asrc + (size_t)row * NT + k0 + sc, Ad + (i * 32 + w * 8) * 64);
    }
  };
  auto B_LOAD = [&](int k0) {
#pragma unroll
    for (int i = 0; i < 8; i++) {
      int hj = k0 + kg * 8 + i;
      int prow = ((hj >> 6) << 7) + (hj & 63);
      bv[i] = *(const ushort4_t*)(P + ((size_t)b * NP + prow) * NN + n0 + ng);
    }
  };
  auto B_WRITE = [&](int bi) {
#pragma unroll
    for (int jj = 0; jj < 4; jj++) {
      ushort8_t pk;
#pragma unroll
      for (int i = 0; i < 8; i++) pk[i] = bv[i][jj];
      *(ushort8_t*)&Bsh[bi * 9216 + (ng + jj) * 72 + kg * 8] = pk;
    }
  };

  A_STAGE(0, 0);
  B_LOAD(0);
  B_WRITE(0);
  __syncthreads();
  int cur = 0;
#pragma unroll 1
  for (int it = 0; it < 8; it++) {
    if (it + 1 < 8) {
      A_STAGE(cur ^ 1, (it + 1) * 64);
      B_LOAD((it + 1) * 64);
    }
    const ushort_t* Ar = Ash + cur * 8192;
    const ushort_t* Br = Bsh + cur * 9216;
#pragma unroll
    for (int ks = 0; ks < 2; ks++) {
      const int col = ks * 32 + kq;
      bf16x8 af[4], bf[4];
#pragma unroll
      for (int f = 0; f < 4; f++) {
        af[f] = *(const bf16x8*)&Ar[(wm + f * 16 + fr) * 64 + (col ^ swz)];
        bf[f] = *(const bf16x8*)&Br[(wn + f * 16 + fr) * 72 + col];
      }
#pragma unroll
      for (int fm = 0; fm < 4; fm++)
#pragma unroll
        for (int fn = 0; fn < 4; fn++)
          acc[fm][fn] = mfma16(af[fm], bf[fn], acc[fm][fn]);
    }
    if (it + 1 < 8) B_WRITE(cur ^ 1);
    __syncthreads();
    cur ^= 1;
  }
  const float al = alpha[0];
  const int col = lane & 15, rb = (lane >> 4) * 4;
#pragma unroll
  for (int fm = 0; fm < 4; fm++)
#pragma unroll
    for (int rg = 0; rg < 4; rg++) {
      int row = m0 + wm + fm * 16 + rb + rg;
      float bias = bout[row];
#pragma unroll
      for (int fn = 0; fn < 4; fn++) {
        int cc = n0 + wn + fn * 16 + col;
        size_t idx = ((size_t)b * NC + row) * NN + cc;
        out[idx] = x[idx] + al * (acc[fm][fn][rg] + bias);
      }
    }
}

// ---------------------------------------------------------------------------
extern "C" void kernel_launch(void* const* d_in, const int* in_sizes, int n_in,
                              void* d_out, int out_size, void* d_ws, size_t ws_size,
                              hipStream_t stream) {
  const float* x = (const float*)d_in[0];
  const float* Wqkv = (const float*)d_in[1];
  const float* bqkv = (const float*)d_in[2];
  const float* Wr = (const float*)d_in[3];
  const float* br = (const float*)d_in[4];
  const float* Wout = (const float*)d_in[5];
  const float* bout = (const float*)d_in[6];
  const float* alpha = (const float*)d_in[7];
  float* out = (float*)d_out;

  char* ws = (char*)d_ws;
  ushort_t* P = (ushort_t*)ws;                    // [0, 134217728)
  ushort_t* xb = (ushort_t*)(ws + 134217728);     // 33.5MB (dead after k3)
  ushort_t* QKVRb = (ushort_t*)(ws + 134217728);  //   aliases xb: 25.2MB (k4a+)
  ushort_t* xt = (ushort_t*)(ws + 167772160);     // 33.5MB (dead after k1)
  ushort_t* XRbT = (ushort_t*)(ws + 167772160);   //   aliases xt: 8.4MB (k3+)
  ushort_t* Wrb = (ushort_t*)(ws + 201326592);    // 0.5MB
  float* sPpart = (float*)(ws + 201850880);       // 4.2MB (dead after k2r)
  ushort_t* Wqkvb = (ushort_t*)(ws + 201850880);  //   aliases sPpart: 0.4MB
  float* sP = (float*)(ws + 206045184);           // 64KB
  ushort_t* Tmb = (ushort_t*)(ws + 206110720);    // 4.2MB -> end 210305024

  k0_cvt<<<dim3(64, 4, 16), 256, 0, stream>>>(x, xb, xt);
  cvt_f2b_k<<<256, 256, 0, stream>>>(Wr, Wrb);
  k1_proj<<<4096, 256, 0, stream>>>(Wrb, xt, br, P);
  k2_softmax<<<dim3(64, 16), 512, 0, stream>>>(P, sPpart);
  k2r_reduce<<<64, 256, 0, stream>>>(sPpart, sP);
  cvt_f2b_k<<<192, 256, 0, stream>>>(Wqkv, Wqkvb);  // after k2r (aliases sPpart)
  k3_pool<<<256, 256, 0, stream>>>(xb, P, XRbT);    // writes into xt region (xt dead)
  k4a_qkvr<<<768, 256, 0, stream>>>(Wqkvb, XRbT, bqkv, sP, QKVRb);
  k4b_attn<<<128, 256, 0, stream>>>(QKVRb, Wout, Tmb);
  k5_out<<<1024, 256, 0, stream>>>(x, P, Tmb, bout, alpha, out);
}

// Round 10
// 334.116 us; speedup vs baseline: 1.1465x; 1.0159x over previous
//
#include <hip/hip_runtime.h>
#include <cstdint>

typedef unsigned short ushort_t;
typedef __attribute__((ext_vector_type(4))) unsigned short ushort4_t;
typedef __attribute__((ext_vector_type(8))) unsigned short ushort8_t;
typedef __attribute__((ext_vector_type(8))) __bf16 bf16x8;
typedef __attribute__((ext_vector_type(4))) float f32x4;

constexpr int NB = 16;    // batch
constexpr int NC = 256;   // channels C (== E)
constexpr int NN = 4096;  // tokens N = H*W
constexpr int NP = 1024;  // region-proj channels = 2*R*heads
constexpr int NT = 512;   // heads * R (Rq columns of T)
constexpr int NO = 768;   // 3*E rows of Wqkv

static __device__ __forceinline__ ushort_t f2b(float f) {
  uint32_t u = __builtin_bit_cast(uint32_t, f);
  u += 0x7FFFu + ((u >> 16) & 1u);
  return (ushort_t)(u >> 16);
}
static __device__ __forceinline__ float b2f(ushort_t h) {
  return __builtin_bit_cast(float, (uint32_t)h << 16);
}
static __device__ __forceinline__ f32x4 mfma16(bf16x8 a, bf16x8 b, f32x4 c) {
  return __builtin_amdgcn_mfma_f32_16x16x32_bf16(a, b, c, 0, 0, 0);
}
typedef __attribute__((address_space(1))) const unsigned int guint;
typedef __attribute__((address_space(3))) unsigned int luint;
static __device__ __forceinline__ void glds16(const void* g, void* l) {
  __builtin_amdgcn_global_load_lds((guint*)g, (luint*)l, 16, 0, 0);
}

// ---------------------------------------------------------------------------
// Single-buffer 128x128 GEMM core (m97-style): BK=64, XOR-swizzled LDS,
// 2 barriers per K-step. Uses SH[0,16384) (As at 0, Bs at 8192 elems).
// ---------------------------------------------------------------------------
template <int KITERS>
__device__ __forceinline__ void gemm_core_sb(const ushort_t* __restrict__ Asrc, size_t lda,
                                             const ushort_t* __restrict__ Bsrc, size_t ldb,
                                             ushort_t* SH, f32x4 (&acc)[4][4], int tid) {
  const int l = tid & 63, w = tid >> 6;
  const int fr = l & 15, kq = (l >> 4) * 8;
  const int rr = l >> 3;
  const int sc = ((l & 7) ^ rr) << 3;
  const int swz = (fr & 7) << 3;
  const int wm = (w >> 1) * 64, wn = (w & 1) * 64;
  ushort_t* As = SH;
  ushort_t* Bs = SH + 8192;
#pragma unroll 1
  for (int it = 0; it < KITERS; it++) {
    const size_t k0 = (size_t)it * 64;
#pragma unroll
    for (int i = 0; i < 4; i++) {
      const int row = i * 32 + w * 8 + rr;
      glds16(Asrc + (size_t)row * lda + k0 + sc, As + (i * 32 + w * 8) * 64);
      glds16(Bsrc + (size_t)row * ldb + k0 + sc, Bs + (i * 32 + w * 8) * 64);
    }
    __syncthreads();
#pragma unroll
    for (int ks = 0; ks < 2; ks++) {
      const int col = ks * 32 + kq;
      bf16x8 af[4], bf[4];
#pragma unroll
      for (int f = 0; f < 4; f++) {
        af[f] = *(const bf16x8*)&As[(wm + f * 16 + fr) * 64 + (col ^ swz)];
        bf[f] = *(const bf16x8*)&Bs[(wn + f * 16 + fr) * 64 + (col ^ swz)];
      }
#pragma unroll
      for (int fm = 0; fm < 4; fm++)
#pragma unroll
        for (int fn = 0; fn < 4; fn++)
          acc[fm][fn] = mfma16(af[fm], bf[fn], acc[fm][fn]);
    }
    __syncthreads();
  }
}

// ---------------------------------------------------------------------------
// K0: x (f32 [b][c][n]) -> xb (bf16 [b][c][n]) and xt (bf16 [b][n][c])
// ---------------------------------------------------------------------------
__global__ __launch_bounds__(256) void k0_cvt(const float* __restrict__ x,
                                              ushort_t* __restrict__ xb,
                                              ushort_t* __restrict__ xt) {
  __shared__ ushort_t tr[64][88];
  const int tid = threadIdx.x;
  const int n0 = blockIdx.x * 64, c0 = blockIdx.y * 64, b = blockIdx.z;
  const int cr = (tid >> 4) * 4;
  const int nc4 = (tid & 15) * 4;
#pragma unroll
  for (int i = 0; i < 4; i++) {
    size_t idx = ((size_t)b * NC + c0 + cr + i) * NN + n0 + nc4;
    float4 v = *(const float4*)(x + idx);
    ushort4_t o;
    o[0] = f2b(v.x); o[1] = f2b(v.y); o[2] = f2b(v.z); o[3] = f2b(v.w);
    *(ushort4_t*)(xb + idx) = o;
    tr[nc4 + 0][cr + i] = o[0];
    tr[nc4 + 1][cr + i] = o[1];
    tr[nc4 + 2][cr + i] = o[2];
    tr[nc4 + 3][cr + i] = o[3];
  }
  __syncthreads();
  const int nr = tid >> 2, cc0 = (tid & 3) * 16;
  size_t odx = ((size_t)b * NN + n0 + nr) * NC + c0 + cc0;
  *(ushort8_t*)(xt + odx) = *(const ushort8_t*)&tr[nr][cc0];
  *(ushort8_t*)(xt + odx + 8) = *(const ushort8_t*)&tr[nr][cc0 + 8];
}

// generic f32 -> bf16 (count multiple of 1024)
__global__ __launch_bounds__(256) void cvt_f2b_k(const float* __restrict__ src,
                                                 ushort_t* __restrict__ dst) {
  int i = (blockIdx.x * 256 + threadIdx.x) * 4;
  float4 v = *(const float4*)(src + i);
  ushort4_t o;
  o[0] = f2b(v.x); o[1] = f2b(v.y); o[2] = f2b(v.z); o[3] = f2b(v.w);
  *(ushort4_t*)(dst + i) = o;
}

// ---------------------------------------------------------------------------
// K1: P[b,p,n] = Wrb[p,:]·xt[b,n,:] + br[p]   (bf16 out, pre-softmax)
// 128x128, single-buffer gemm_core_sb, 32 KB LDS (5 blocks/CU), DIRECT
// scalar stores (R4's measured-best 71us config; restage epilogue reverted —
// it cost occupancy 5->4 blocks/CU and 20us, R9 post-mortem).
// ---------------------------------------------------------------------------
__global__ __launch_bounds__(256) void k1_proj(const ushort_t* __restrict__ Wrb,
                                               const ushort_t* __restrict__ xt,
                                               const float* __restrict__ br,
                                               ushort_t* __restrict__ P) {
  __shared__ __align__(16) ushort_t SH[16384];  // 32 KB
  const int tid = threadIdx.x;
  const int ord = blockIdx.x;
  const int L = (ord & 7) * 512 + (ord >> 3);
  const int m0 = (L & 7) * 128;
  const int n0 = ((L >> 3) & 31) * 128;
  const int b = L >> 8;
  const int lane = tid & 63, w = tid >> 6;
  const int wm = (w >> 1) * 64, wn = (w & 1) * 64;
  f32x4 acc[4][4] = {};
  gemm_core_sb<4>(Wrb + (size_t)m0 * NC, NC,
                  xt + ((size_t)b * NN + n0) * NC, NC, SH, acc, tid);
  const int col = lane & 15, rb = (lane >> 4) * 4;
#pragma unroll
  for (int fm = 0; fm < 4; fm++)
#pragma unroll
    for (int rg = 0; rg < 4; rg++) {
      int row = m0 + wm + fm * 16 + rb + rg;
      float bias = br[row];
#pragma unroll
      for (int fn = 0; fn < 4; fn++) {
        int cc = n0 + wn + fn * 16 + col;
        P[((size_t)b * NP + row) * NN + cc] = f2b(acc[fm][fn][rg] + bias);
      }
    }
}

// ---------------------------------------------------------------------------
// K2: softmax over p (1024) per (b,n) column, in-place; rowsum partials.
// 512 thr; rows held in registers (single global read).
// ---------------------------------------------------------------------------
__global__ __launch_bounds__(512) void k2_softmax(ushort_t* __restrict__ P,
                                                  float* __restrict__ sPpart) {
  __shared__ float red[64][64];
  __shared__ float Mf[64], If[64];
  const int tid = threadIdx.x;
  const int n0 = blockIdx.x * 64, b = blockIdx.y;
  const int cg = tid & 7, pg = tid >> 3;
  ushort_t* base = P + (size_t)b * NP * NN + n0 + cg * 8;

  ushort8_t v[16];
  float m[8];
#pragma unroll
  for (int j = 0; j < 8; j++) m[j] = -3.0e38f;
#pragma unroll
  for (int r = 0; r < 16; r++) {
    v[r] = *(const ushort8_t*)(base + (size_t)(pg * 16 + r) * NN);
#pragma unroll
    for (int j = 0; j < 8; j++) m[j] = fmaxf(m[j], b2f(v[r][j]));
  }
#pragma unroll
  for (int j = 0; j < 8; j++) red[pg][cg * 8 + j] = m[j];
  __syncthreads();
  if (tid < 64) {
    float M = -3.0e38f;
    for (int g = 0; g < 64; g++) M = fmaxf(M, red[g][tid]);
    Mf[tid] = M;
  }
  __syncthreads();
  float mj[8], s[8];
#pragma unroll
  for (int j = 0; j < 8; j++) { mj[j] = Mf[cg * 8 + j]; s[j] = 0.f; }
#pragma unroll
  for (int r = 0; r < 16; r++)
#pragma unroll
    for (int j = 0; j < 8; j++) s[j] += __expf(b2f(v[r][j]) - mj[j]);
#pragma unroll
  for (int j = 0; j < 8; j++) red[pg][cg * 8 + j] = s[j];
  __syncthreads();
  if (tid < 64) {
    float S = 0.f;
    for (int g = 0; g < 64; g++) S += red[g][tid];
    If[tid] = 1.f / S;
  }
  __syncthreads();
  float ij[8];
#pragma unroll
  for (int j = 0; j < 8; j++) ij[j] = If[cg * 8 + j];
#pragma unroll
  for (int r = 0; r < 16; r++) {
    int p = pg * 16 + r;
    ushort8_t o;
    float rs = 0.f;
#pragma unroll
    for (int j = 0; j < 8; j++) {
      float e = __expf(b2f(v[r][j]) - mj[j]) * ij[j];
      o[j] = f2b(e);
      rs += e;
    }
    *(ushort8_t*)(base + (size_t)p * NN) = o;
    rs += __shfl_xor(rs, 1, 64);
    rs += __shfl_xor(rs, 2, 64);
    rs += __shfl_xor(rs, 4, 64);
    if (cg == 0) sPpart[((size_t)blockIdx.x * NB + b) * NP + p] = rs;
  }
}

// K2r: sP[b,p] = sum over 64 n-blocks
__global__ __launch_bounds__(256) void k2r_reduce(const float* __restrict__ sPpart,
                                                  float* __restrict__ sP) {
  int idx = blockIdx.x * 256 + threadIdx.x;
  float s = 0.f;
#pragma unroll 8
  for (int bx = 0; bx < 64; bx++) s += sPpart[(size_t)bx * (NB * NP) + idx];
  sP[idx] = s;
}

// ---------------------------------------------------------------------------
// K3: XRbT[b][p][c] = f2b( sum_n xb[b,c,n]·P[b,p,n] )  (transposed bf16 out)
// Full K=4096, grid 256, double-buffered BK=64 pipeline.
// ---------------------------------------------------------------------------
__global__ __launch_bounds__(256) void k3_pool(const ushort_t* __restrict__ xb,
                                               const ushort_t* __restrict__ P,
                                               ushort_t* __restrict__ XRbT) {
  __shared__ __align__(16) ushort_t SH[4 * 8192];  // 64 KB dbuf
  const int tid = threadIdx.x;
  const int ord = blockIdx.x;  // 256 blocks
  const int L = (ord & 7) * 32 + (ord >> 3);
  const int m0 = (L & 1) * 128;         // c
  const int n0 = ((L >> 1) & 7) * 128;  // p
  const int b = L >> 4;
  const int l = tid & 63, w = tid >> 6;
  const int fr = l & 15, kq = (l >> 4) * 8;
  const int rr = l >> 3;
  const int sc = ((l & 7) ^ rr) << 3;
  const int swz = (fr & 7) << 3;
  const int wm = (w >> 1) * 64, wn = (w & 1) * 64;
  const ushort_t* Asrc = xb + ((size_t)b * NC + m0) * NN;
  const ushort_t* Bsrc = P + ((size_t)b * NP + n0) * NN;
  f32x4 acc[4][4] = {};

  auto STAGE = [&](int bi, size_t k0) {
    ushort_t* Ad = SH + bi * 8192;
    ushort_t* Bd = SH + 16384 + bi * 8192;
#pragma unroll
    for (int i = 0; i < 4; i++) {
      const int row = i * 32 + w * 8 + rr;
      glds16(Asrc + (size_t)row * NN + k0 + sc, Ad + (i * 32 + w * 8) * 64);
      glds16(Bsrc + (size_t)row * NN + k0 + sc, Bd + (i * 32 + w * 8) * 64);
    }
  };

  STAGE(0, 0);
  __syncthreads();
  int cur = 0;
#pragma unroll 1
  for (int it = 0; it < 64; it++) {
    if (it + 1 < 64) STAGE(cur ^ 1, (size_t)(it + 1) * 64);
    const ushort_t* Ar = SH + cur * 8192;
    const ushort_t* Br = SH + 16384 + cur * 8192;
#pragma unroll
    for (int ks = 0; ks < 2; ks++) {
      const int col = ks * 32 + kq;
      bf16x8 af[4], bf[4];
#pragma unroll
      for (int f = 0; f < 4; f++) {
        af[f] = *(const bf16x8*)&Ar[(wm + f * 16 + fr) * 64 + (col ^ swz)];
        bf[f] = *(const bf16x8*)&Br[(wn + f * 16 + fr) * 64 + (col ^ swz)];
      }
#pragma unroll
      for (int fm = 0; fm < 4; fm++)
#pragma unroll
        for (int fn = 0; fn < 4; fn++)
          acc[fm][fn] = mfma16(af[fm], bf[fn], acc[fm][fn]);
    }
    __syncthreads();
    cur ^= 1;
  }
  // transposed epilogue: stage[p_local][c_local] stride 136, 2 passes
  const int colc = l & 15, rb = (l >> 4) * 4;
#pragma unroll
  for (int pp = 0; pp < 2; pp++) {
    if ((w & 1) == pp) {
#pragma unroll
      for (int fm = 0; fm < 4; fm++)
#pragma unroll
        for (int rg = 0; rg < 4; rg++) {
          const int cl = wm + fm * 16 + rb + rg;  // 0..127
#pragma unroll
          for (int fn = 0; fn < 4; fn++) {
            const int pl = fn * 16 + colc;  // 0..63
            SH[pl * 136 + cl] = f2b(acc[fm][fn][rg]);
          }
        }
    }
    __syncthreads();
    const int prow = tid >> 2, cch = (tid & 3) * 32;
    ushort_t* dst = XRbT + ((size_t)b * NP + n0 + pp * 64 + prow) * NC + m0 + cch;
    const ushort_t* s = &SH[prow * 136 + cch];
#pragma unroll
    for (int j = 0; j < 4; j++)
      *(ushort8_t*)(dst + j * 8) = *(const ushort8_t*)(s + j * 8);
    __syncthreads();
  }
}

// ---------------------------------------------------------------------------
// K4a: QKVRb[b][o][p] = f2b( Wqkvb[o,:]·XRbT[b,p,:] + bqkv[o]·sP[b,p] )
// ---------------------------------------------------------------------------
__global__ __launch_bounds__(256) void k4a_qkvr(const ushort_t* __restrict__ Wqkvb,
                                                const ushort_t* __restrict__ XRbT,
                                                const float* __restrict__ bqkv,
                                                const float* __restrict__ sP,
                                                ushort_t* __restrict__ QKVRb) {
  __shared__ __align__(16) ushort_t SH[2 * 8192];  // 32 KB single-buf
  const int tid = threadIdx.x;
  const int ord = blockIdx.x;
  const int L = (ord & 7) * 96 + (ord >> 3);
  const int m0 = (L % 6) * 128;
  const int rest = L / 6;
  const int n0 = (rest & 7) * 128;
  const int b = rest >> 3;
  const int lane = tid & 63, w = tid >> 6;
  const int wm = (w >> 1) * 64, wn = (w & 1) * 64;
  f32x4 acc[4][4] = {};
  gemm_core_sb<4>(Wqkvb + (size_t)m0 * NC, NC,
                  XRbT + ((size_t)b * NP + n0) * NC, NC, SH, acc, tid);
  const int col = lane & 15, rb = (lane >> 4) * 4;
  float spv[4];
#pragma unroll
  for (int fn = 0; fn < 4; fn++) spv[fn] = sP[(size_t)b * NP + n0 + wn + fn * 16 + col];
#pragma unroll
  for (int fm = 0; fm < 4; fm++)
#pragma unroll
    for (int rg = 0; rg < 4; rg++) {
      int row = m0 + wm + fm * 16 + rb + rg;
      float bq = bqkv[row];
#pragma unroll
      for (int fn = 0; fn < 4; fn++) {
        int cc = n0 + wn + fn * 16 + col;
        QKVRb[((size_t)b * NO + row) * NP + cc] = f2b(acc[fm][fn][rg] + bq * spv[fn]);
      }
    }
}

// ---------------------------------------------------------------------------
// K4b: per-(b,h) tiny attention + Wout fold -> Tmb (bf16)
// ---------------------------------------------------------------------------
__global__ __launch_bounds__(256) void k4b_attn(const ushort_t* __restrict__ QKVRb,
                                                const float* __restrict__ Wout,
                                                ushort_t* __restrict__ Tmb) {
  const int b = blockIdx.x >> 3, h = blockIdx.x & 7;
  const int tid = threadIdx.x;
  __shared__ float qf[96][64];       // q(0:32) k(32:64) v(64:96)
  __shared__ float attn_sT[64][65];  // [k][q]
  __shared__ float vals_s[32][64];
#pragma unroll
  for (int i = 0; i < 3; i++) {
    int u = i * 256 + tid;
    int rw = u >> 3, jc = (u & 7) * 8;
    int p0 = h * 128 + ((rw < 32) ? 0 : 64);
    ushort8_t v = *(const ushort8_t*)(QKVRb + ((size_t)b * NO + h * 96 + rw) * NP + p0 + jc);
#pragma unroll
    for (int j = 0; j < 8; j++) qf[rw][jc + j] = b2f(v[j]);
  }
  __syncthreads();
  const int lj = tid & 63;
  const int rq = tid >> 6;
  float kcol[32];
#pragma unroll
  for (int dd = 0; dd < 32; dd++) kcol[dd] = qf[32 + dd][lj];
  const float isc = 0.17677669529663687f;
#pragma unroll
  for (int r = 0; r < 16; r++) {
    int qi = r * 4 + rq;
    float a = 0.f;
#pragma unroll
    for (int dd = 0; dd < 32; dd++) a += qf[dd][qi] * kcol[dd];
    attn_sT[lj][qi] = a * isc;
  }
  __syncthreads();
  if (tid < 64) {
    float m = -3e38f;
    for (int k = 0; k < 64; k++) m = fmaxf(m, attn_sT[k][tid]);
    float s = 0.f;
    for (int k = 0; k < 64; k++) {
      float e = __expf(attn_sT[k][tid] - m);
      attn_sT[k][tid] = e;
      s += e;
    }
    float inv = 1.f / s;
    for (int k = 0; k < 64; k++) attn_sT[k][tid] *= inv;
  }
  __syncthreads();
  float acol[64];
#pragma unroll
  for (int k = 0; k < 64; k++) acol[k] = attn_sT[k][lj];
#pragma unroll
  for (int r = 0; r < 8; r++) {
    int dd = r * 4 + rq;
    float a = 0.f;
#pragma unroll
    for (int k = 0; k < 64; k++) a += qf[64 + dd][k] * acol[k];
    vals_s[dd][lj] = a;
  }
  __syncthreads();
  float vcol[32];
#pragma unroll
  for (int dd = 0; dd < 32; dd++) vcol[dd] = vals_s[dd][lj];
  for (int r = 0; r < 64; r++) {
    int c = r * 4 + rq;
    const float4* wp = (const float4*)(Wout + (size_t)c * NC + h * 32);
    float a = 0.f;
#pragma unroll
    for (int t = 0; t < 8; t++) {
      float4 w = wp[t];
      a += w.x * vcol[t * 4] + w.y * vcol[t * 4 + 1] + w.z * vcol[t * 4 + 2] +
           w.w * vcol[t * 4 + 3];
    }
    Tmb[((size_t)b * NC + c) * NT + h * 64 + lj] = f2b(a);
  }
}

// ---------------------------------------------------------------------------
// K5: out = x + alpha*(Tmb·Pq + bout). Pipelined: A glds dbuf; B reg-staged
// (load-early / ds_write-late) into pad-72 dbuf LDS tile.
// ---------------------------------------------------------------------------
__global__ __launch_bounds__(256) void k5_out(const float* __restrict__ x,
                                              const ushort_t* __restrict__ P,
                                              const ushort_t* __restrict__ Tmb,
                                              const float* __restrict__ bout,
                                              const float* __restrict__ alpha,
                                              float* __restrict__ out) {
  __shared__ __align__(16) ushort_t Ash[2 * 8192];  // 32 KB
  __shared__ __align__(16) ushort_t Bsh[2 * 9216];  // 36 KB (128 rows x 72)
  const int tid = threadIdx.x;
  const int ord = blockIdx.x;
  const int L = (ord & 7) * 128 + (ord >> 3);
  const int m0 = (L & 1) * 128;
  const int n0 = ((L >> 1) & 31) * 128;
  const int b = L >> 6;
  const int lane = tid & 63, w = tid >> 6;
  const int wm = (w >> 1) * 64, wn = (w & 1) * 64;
  const int fr = lane & 15, kq = (lane >> 4) * 8;
  const int rr = lane >> 3, sc = ((lane & 7) ^ rr) << 3;
  const int swz = (fr & 7) << 3;
  const ushort_t* Asrc = Tmb + ((size_t)b * NC + m0) * NT;
  const int kg = tid >> 5, ng = (tid & 31) * 4;  // B stage: 8 k-rows x 4 n
  f32x4 acc[4][4] = {};
  ushort4_t bv[8];

  auto A_STAGE = [&](int bi, int k0) {
    ushort_t* Ad = Ash + bi * 8192;
#pragma unroll
    for (int i = 0; i < 4; i++) {
      const int row = i * 32 + w * 8 + rr;
      glds16(Asrc + (size_t)row * NT + k0 + sc, Ad + (i * 32 + w * 8) * 64);
    }
  };
  auto B_LOAD = [&](int k0) {
#pragma unroll
    for (int i = 0; i < 8; i++) {
      int hj = k0 + kg * 8 + i;
      int prow = ((hj >> 6) << 7) + (hj & 63);
      bv[i] = *(const ushort4_t*)(P + ((size_t)b * NP + prow) * NN + n0 + ng);
    }
  };
  auto B_WRITE = [&](int bi) {
#pragma unroll
    for (int jj = 0; jj < 4; jj++) {
      ushort8_t pk;
#pragma unroll
      for (int i = 0; i < 8; i++) pk[i] = bv[i][jj];
      *(ushort8_t*)&Bsh[bi * 9216 + (ng + jj) * 72 + kg * 8] = pk;
    }
  };

  A_STAGE(0, 0);
  B_LOAD(0);
  B_WRITE(0);
  __syncthreads();
  int cur = 0;
#pragma unroll 1
  for (int it = 0; it < 8; it++) {
    if (it + 1 < 8) {
      A_STAGE(cur ^ 1, (it + 1) * 64);
      B_LOAD((it + 1) * 64);
    }
    const ushort_t* Ar = Ash + cur * 8192;
    const ushort_t* Br = Bsh + cur * 9216;
#pragma unroll
    for (int ks = 0; ks < 2; ks++) {
      const int col = ks * 32 + kq;
      bf16x8 af[4], bf[4];
#pragma unroll
      for (int f = 0; f < 4; f++) {
        af[f] = *(const bf16x8*)&Ar[(wm + f * 16 + fr) * 64 + (col ^ swz)];
        bf[f] = *(const bf16x8*)&Br[(wn + f * 16 + fr) * 72 + col];
      }
#pragma unroll
      for (int fm = 0; fm < 4; fm++)
#pragma unroll
        for (int fn = 0; fn < 4; fn++)
          acc[fm][fn] = mfma16(af[fm], bf[fn], acc[fm][fn]);
    }
    if (it + 1 < 8) B_WRITE(cur ^ 1);
    __syncthreads();
    cur ^= 1;
  }
  const float al = alpha[0];
  const int col = lane & 15, rb = (lane >> 4) * 4;
#pragma unroll
  for (int fm = 0; fm < 4; fm++)
#pragma unroll
    for (int rg = 0; rg < 4; rg++) {
      int row = m0 + wm + fm * 16 + rb + rg;
      float bias = bout[row];
#pragma unroll
      for (int fn = 0; fn < 4; fn++) {
        int cc = n0 + wn + fn * 16 + col;
        size_t idx = ((size_t)b * NC + row) * NN + cc;
        out[idx] = x[idx] + al * (acc[fm][fn][rg] + bias);
      }
    }
}

// ---------------------------------------------------------------------------
extern "C" void kernel_launch(void* const* d_in, const int* in_sizes, int n_in,
                              void* d_out, int out_size, void* d_ws, size_t ws_size,
                              hipStream_t stream) {
  const float* x = (const float*)d_in[0];
  const float* Wqkv = (const float*)d_in[1];
  const float* bqkv = (const float*)d_in[2];
  const float* Wr = (const float*)d_in[3];
  const float* br = (const float*)d_in[4];
  const float* Wout = (const float*)d_in[5];
  const float* bout = (const float*)d_in[6];
  const float* alpha = (const float*)d_in[7];
  float* out = (float*)d_out;

  char* ws = (char*)d_ws;
  ushort_t* P = (ushort_t*)ws;                    // [0, 134217728)
  ushort_t* xb = (ushort_t*)(ws + 134217728);     // 33.5MB (dead after k3)
  ushort_t* QKVRb = (ushort_t*)(ws + 134217728);  //   aliases xb: 25.2MB (k4a+)
  ushort_t* xt = (ushort_t*)(ws + 167772160);     // 33.5MB (dead after k1)
  ushort_t* XRbT = (ushort_t*)(ws + 167772160);   //   aliases xt: 8.4MB (k3+)
  ushort_t* Wrb = (ushort_t*)(ws + 201326592);    // 0.5MB
  float* sPpart = (float*)(ws + 201850880);       // 4.2MB (dead after k2r)
  ushort_t* Wqkvb = (ushort_t*)(ws + 201850880);  //   aliases sPpart: 0.4MB
  float* sP = (float*)(ws + 206045184);           // 64KB
  ushort_t* Tmb = (ushort_t*)(ws + 206110720);    // 4.2MB -> end 210305024

  k0_cvt<<<dim3(64, 4, 16), 256, 0, stream>>>(x, xb, xt);
  cvt_f2b_k<<<256, 256, 0, stream>>>(Wr, Wrb);
  k1_proj<<<4096, 256, 0, stream>>>(Wrb, xt, br, P);
  k2_softmax<<<dim3(64, 16), 512, 0, stream>>>(P, sPpart);
  k2r_reduce<<<64, 256, 0, stream>>>(sPpart, sP);
  cvt_f2b_k<<<192, 256, 0, stream>>>(Wqkv, Wqkvb);  // after k2r (aliases sPpart)
  k3_pool<<<256, 256, 0, stream>>>(xb, P, XRbT);    // writes into xt region (xt dead)
  k4a_qkvr<<<768, 256, 0, stream>>>(Wqkvb, XRbT, bqkv, sP, QKVRb);
  k4b_attn<<<128, 256, 0, stream>>>(QKVRb, Wout, Tmb);
  k5_out<<<1024, 256, 0, stream>>>(x, P, Tmb, bout, alpha, out);
}

// Round 11
// 329.351 us; speedup vs baseline: 1.1631x; 1.0145x over previous
//
#include <hip/hip_runtime.h>
#include <cstdint>

typedef unsigned short ushort_t;
typedef __attribute__((ext_vector_type(4))) unsigned short ushort4_t;
typedef __attribute__((ext_vector_type(8))) unsigned short ushort8_t;
typedef __attribute__((ext_vector_type(8))) __bf16 bf16x8;
typedef __attribute__((ext_vector_type(4))) float f32x4;

constexpr int NB = 16;    // batch
constexpr int NC = 256;   // channels C (== E)
constexpr int NN = 4096;  // tokens N = H*W
constexpr int NP = 1024;  // region-proj channels = 2*R*heads
constexpr int NT = 512;   // heads * R (Rq columns of T)
constexpr int NO = 768;   // 3*E rows of Wqkv

static __device__ __forceinline__ ushort_t f2b(float f) {
  uint32_t u = __builtin_bit_cast(uint32_t, f);
  u += 0x7FFFu + ((u >> 16) & 1u);
  return (ushort_t)(u >> 16);
}
static __device__ __forceinline__ float b2f(ushort_t h) {
  return __builtin_bit_cast(float, (uint32_t)h << 16);
}
static __device__ __forceinline__ f32x4 mfma16(bf16x8 a, bf16x8 b, f32x4 c) {
  return __builtin_amdgcn_mfma_f32_16x16x32_bf16(a, b, c, 0, 0, 0);
}
typedef __attribute__((address_space(1))) const unsigned int guint;
typedef __attribute__((address_space(3))) unsigned int luint;
static __device__ __forceinline__ void glds16(const void* g, void* l) {
  __builtin_amdgcn_global_load_lds((guint*)g, (luint*)l, 16, 0, 0);
}

// ---------------------------------------------------------------------------
// Single-buffer 128x128 GEMM core (m97-style): BK=64, XOR-swizzled LDS,
// 2 barriers per K-step. Uses SH[0,16384) (As at 0, Bs at 8192 elems).
// ---------------------------------------------------------------------------
template <int KITERS>
__device__ __forceinline__ void gemm_core_sb(const ushort_t* __restrict__ Asrc, size_t lda,
                                             const ushort_t* __restrict__ Bsrc, size_t ldb,
                                             ushort_t* SH, f32x4 (&acc)[4][4], int tid) {
  const int l = tid & 63, w = tid >> 6;
  const int fr = l & 15, kq = (l >> 4) * 8;
  const int rr = l >> 3;
  const int sc = ((l & 7) ^ rr) << 3;
  const int swz = (fr & 7) << 3;
  const int wm = (w >> 1) * 64, wn = (w & 1) * 64;
  ushort_t* As = SH;
  ushort_t* Bs = SH + 8192;
#pragma unroll 1
  for (int it = 0; it < KITERS; it++) {
    const size_t k0 = (size_t)it * 64;
#pragma unroll
    for (int i = 0; i < 4; i++) {
      const int row = i * 32 + w * 8 + rr;
      glds16(Asrc + (size_t)row * lda + k0 + sc, As + (i * 32 + w * 8) * 64);
      glds16(Bsrc + (size_t)row * ldb + k0 + sc, Bs + (i * 32 + w * 8) * 64);
    }
    __syncthreads();
#pragma unroll
    for (int ks = 0; ks < 2; ks++) {
      const int col = ks * 32 + kq;
      bf16x8 af[4], bf[4];
#pragma unroll
      for (int f = 0; f < 4; f++) {
        af[f] = *(const bf16x8*)&As[(wm + f * 16 + fr) * 64 + (col ^ swz)];
        bf[f] = *(const bf16x8*)&Bs[(wn + f * 16 + fr) * 64 + (col ^ swz)];
      }
#pragma unroll
      for (int fm = 0; fm < 4; fm++)
#pragma unroll
        for (int fn = 0; fn < 4; fn++)
          acc[fm][fn] = mfma16(af[fm], bf[fn], acc[fm][fn]);
    }
    __syncthreads();
  }
}

// ---------------------------------------------------------------------------
// K0: x (f32 [b][c][n]) -> xb (bf16 [b][c][n]) and xt (bf16 [b][n][c])
// ---------------------------------------------------------------------------
__global__ __launch_bounds__(256) void k0_cvt(const float* __restrict__ x,
                                              ushort_t* __restrict__ xb,
                                              ushort_t* __restrict__ xt) {
  __shared__ ushort_t tr[64][88];
  const int tid = threadIdx.x;
  const int n0 = blockIdx.x * 64, c0 = blockIdx.y * 64, b = blockIdx.z;
  const int cr = (tid >> 4) * 4;
  const int nc4 = (tid & 15) * 4;
#pragma unroll
  for (int i = 0; i < 4; i++) {
    size_t idx = ((size_t)b * NC + c0 + cr + i) * NN + n0 + nc4;
    float4 v = *(const float4*)(x + idx);
    ushort4_t o;
    o[0] = f2b(v.x); o[1] = f2b(v.y); o[2] = f2b(v.z); o[3] = f2b(v.w);
    *(ushort4_t*)(xb + idx) = o;
    tr[nc4 + 0][cr + i] = o[0];
    tr[nc4 + 1][cr + i] = o[1];
    tr[nc4 + 2][cr + i] = o[2];
    tr[nc4 + 3][cr + i] = o[3];
  }
  __syncthreads();
  const int nr = tid >> 2, cc0 = (tid & 3) * 16;
  size_t odx = ((size_t)b * NN + n0 + nr) * NC + c0 + cc0;
  *(ushort8_t*)(xt + odx) = *(const ushort8_t*)&tr[nr][cc0];
  *(ushort8_t*)(xt + odx + 8) = *(const ushort8_t*)&tr[nr][cc0 + 8];
}

// generic f32 -> bf16 (count multiple of 1024)
__global__ __launch_bounds__(256) void cvt_f2b_k(const float* __restrict__ src,
                                                 ushort_t* __restrict__ dst) {
  int i = (blockIdx.x * 256 + threadIdx.x) * 4;
  float4 v = *(const float4*)(src + i);
  ushort4_t o;
  o[0] = f2b(v.x); o[1] = f2b(v.y); o[2] = f2b(v.z); o[3] = f2b(v.w);
  *(ushort4_t*)(dst + i) = o;
}

// ---------------------------------------------------------------------------
// K1: P[b,p,n] = Wrb[p,:]·xt[b,n,:] + br[p]   (bf16 out, pre-softmax)
// 128x128, single-buffer gemm_core_sb, 32 KB LDS, direct scalar stores
// (measured-best config; do not touch — see R5/R7/R9 post-mortems).
// ---------------------------------------------------------------------------
__global__ __launch_bounds__(256) void k1_proj(const ushort_t* __restrict__ Wrb,
                                               const ushort_t* __restrict__ xt,
                                               const float* __restrict__ br,
                                               ushort_t* __restrict__ P) {
  __shared__ __align__(16) ushort_t SH[16384];  // 32 KB
  const int tid = threadIdx.x;
  const int ord = blockIdx.x;
  const int L = (ord & 7) * 512 + (ord >> 3);
  const int m0 = (L & 7) * 128;
  const int n0 = ((L >> 3) & 31) * 128;
  const int b = L >> 8;
  const int lane = tid & 63, w = tid >> 6;
  const int wm = (w >> 1) * 64, wn = (w & 1) * 64;
  f32x4 acc[4][4] = {};
  gemm_core_sb<4>(Wrb + (size_t)m0 * NC, NC,
                  xt + ((size_t)b * NN + n0) * NC, NC, SH, acc, tid);
  const int col = lane & 15, rb = (lane >> 4) * 4;
#pragma unroll
  for (int fm = 0; fm < 4; fm++)
#pragma unroll
    for (int rg = 0; rg < 4; rg++) {
      int row = m0 + wm + fm * 16 + rb + rg;
      float bias = br[row];
#pragma unroll
      for (int fn = 0; fn < 4; fn++) {
        int cc = n0 + wn + fn * 16 + col;
        P[((size_t)b * NP + row) * NN + cc] = f2b(acc[fm][fn][rg] + bias);
      }
    }
}

// ---------------------------------------------------------------------------
// K2: softmax over p (1024) per (b,n) column, in-place; rowsum partials.
// ---------------------------------------------------------------------------
__global__ __launch_bounds__(512) void k2_softmax(ushort_t* __restrict__ P,
                                                  float* __restrict__ sPpart) {
  __shared__ float red[64][64];
  __shared__ float Mf[64], If[64];
  const int tid = threadIdx.x;
  const int n0 = blockIdx.x * 64, b = blockIdx.y;
  const int cg = tid & 7, pg = tid >> 3;
  ushort_t* base = P + (size_t)b * NP * NN + n0 + cg * 8;

  ushort8_t v[16];
  float m[8];
#pragma unroll
  for (int j = 0; j < 8; j++) m[j] = -3.0e38f;
#pragma unroll
  for (int r = 0; r < 16; r++) {
    v[r] = *(const ushort8_t*)(base + (size_t)(pg * 16 + r) * NN);
#pragma unroll
    for (int j = 0; j < 8; j++) m[j] = fmaxf(m[j], b2f(v[r][j]));
  }
#pragma unroll
  for (int j = 0; j < 8; j++) red[pg][cg * 8 + j] = m[j];
  __syncthreads();
  if (tid < 64) {
    float M = -3.0e38f;
    for (int g = 0; g < 64; g++) M = fmaxf(M, red[g][tid]);
    Mf[tid] = M;
  }
  __syncthreads();
  float mj[8], s[8];
#pragma unroll
  for (int j = 0; j < 8; j++) { mj[j] = Mf[cg * 8 + j]; s[j] = 0.f; }
#pragma unroll
  for (int r = 0; r < 16; r++)
#pragma unroll
    for (int j = 0; j < 8; j++) s[j] += __expf(b2f(v[r][j]) - mj[j]);
#pragma unroll
  for (int j = 0; j < 8; j++) red[pg][cg * 8 + j] = s[j];
  __syncthreads();
  if (tid < 64) {
    float S = 0.f;
    for (int g = 0; g < 64; g++) S += red[g][tid];
    If[tid] = 1.f / S;
  }
  __syncthreads();
  float ij[8];
#pragma unroll
  for (int j = 0; j < 8; j++) ij[j] = If[cg * 8 + j];
#pragma unroll
  for (int r = 0; r < 16; r++) {
    int p = pg * 16 + r;
    ushort8_t o;
    float rs = 0.f;
#pragma unroll
    for (int j = 0; j < 8; j++) {
      float e = __expf(b2f(v[r][j]) - mj[j]) * ij[j];
      o[j] = f2b(e);
      rs += e;
    }
    *(ushort8_t*)(base + (size_t)p * NN) = o;
    rs += __shfl_xor(rs, 1, 64);
    rs += __shfl_xor(rs, 2, 64);
    rs += __shfl_xor(rs, 4, 64);
    if (cg == 0) sPpart[((size_t)blockIdx.x * NB + b) * NP + p] = rs;
  }
}

// K2r: sP[b,p] = sum over 64 n-blocks
__global__ __launch_bounds__(256) void k2r_reduce(const float* __restrict__ sPpart,
                                                  float* __restrict__ sP) {
  int idx = blockIdx.x * 256 + threadIdx.x;
  float s = 0.f;
#pragma unroll 8
  for (int bx = 0; bx < 64; bx++) s += sPpart[(size_t)bx * (NB * NP) + idx];
  sP[idx] = s;
}

// ---------------------------------------------------------------------------
// K3: XRbT[b][p][c] = f2b( sum_n xb[b,c,n]·P[b,p,n] )  (transposed bf16 out)
// Full K=4096, grid 256, double-buffered BK=64 pipeline.
// ---------------------------------------------------------------------------
__global__ __launch_bounds__(256) void k3_pool(const ushort_t* __restrict__ xb,
                                               const ushort_t* __restrict__ P,
                                               ushort_t* __restrict__ XRbT) {
  __shared__ __align__(16) ushort_t SH[4 * 8192];  // 64 KB dbuf
  const int tid = threadIdx.x;
  const int ord = blockIdx.x;  // 256 blocks
  const int L = (ord & 7) * 32 + (ord >> 3);
  const int m0 = (L & 1) * 128;         // c
  const int n0 = ((L >> 1) & 7) * 128;  // p
  const int b = L >> 4;
  const int l = tid & 63, w = tid >> 6;
  const int fr = l & 15, kq = (l >> 4) * 8;
  const int rr = l >> 3;
  const int sc = ((l & 7) ^ rr) << 3;
  const int swz = (fr & 7) << 3;
  const int wm = (w >> 1) * 64, wn = (w & 1) * 64;
  const ushort_t* Asrc = xb + ((size_t)b * NC + m0) * NN;
  const ushort_t* Bsrc = P + ((size_t)b * NP + n0) * NN;
  f32x4 acc[4][4] = {};

  auto STAGE = [&](int bi, size_t k0) {
    ushort_t* Ad = SH + bi * 8192;
    ushort_t* Bd = SH + 16384 + bi * 8192;
#pragma unroll
    for (int i = 0; i < 4; i++) {
      const int row = i * 32 + w * 8 + rr;
      glds16(Asrc + (size_t)row * NN + k0 + sc, Ad + (i * 32 + w * 8) * 64);
      glds16(Bsrc + (size_t)row * NN + k0 + sc, Bd + (i * 32 + w * 8) * 64);
    }
  };

  STAGE(0, 0);
  __syncthreads();
  int cur = 0;
#pragma unroll 1
  for (int it = 0; it < 64; it++) {
    if (it + 1 < 64) STAGE(cur ^ 1, (size_t)(it + 1) * 64);
    const ushort_t* Ar = SH + cur * 8192;
    const ushort_t* Br = SH + 16384 + cur * 8192;
#pragma unroll
    for (int ks = 0; ks < 2; ks++) {
      const int col = ks * 32 + kq;
      bf16x8 af[4], bf[4];
#pragma unroll
      for (int f = 0; f < 4; f++) {
        af[f] = *(const bf16x8*)&Ar[(wm + f * 16 + fr) * 64 + (col ^ swz)];
        bf[f] = *(const bf16x8*)&Br[(wn + f * 16 + fr) * 64 + (col ^ swz)];
      }
#pragma unroll
      for (int fm = 0; fm < 4; fm++)
#pragma unroll
        for (int fn = 0; fn < 4; fn++)
          acc[fm][fn] = mfma16(af[fm], bf[fn], acc[fm][fn]);
    }
    __syncthreads();
    cur ^= 1;
  }
  // transposed epilogue: stage[p_local][c_local] stride 136, 2 passes
  const int colc = l & 15, rb = (l >> 4) * 4;
#pragma unroll
  for (int pp = 0; pp < 2; pp++) {
    if ((w & 1) == pp) {
#pragma unroll
      for (int fm = 0; fm < 4; fm++)
#pragma unroll
        for (int rg = 0; rg < 4; rg++) {
          const int cl = wm + fm * 16 + rb + rg;  // 0..127
#pragma unroll
          for (int fn = 0; fn < 4; fn++) {
            const int pl = fn * 16 + colc;  // 0..63
            SH[pl * 136 + cl] = f2b(acc[fm][fn][rg]);
          }
        }
    }
    __syncthreads();
    const int prow = tid >> 2, cch = (tid & 3) * 32;
    ushort_t* dst = XRbT + ((size_t)b * NP + n0 + pp * 64 + prow) * NC + m0 + cch;
    const ushort_t* s = &SH[prow * 136 + cch];
#pragma unroll
    for (int j = 0; j < 4; j++)
      *(ushort8_t*)(dst + j * 8) = *(const ushort8_t*)(s + j * 8);
    __syncthreads();
  }
}

// ---------------------------------------------------------------------------
// K4f: FUSED per-(b,h) QKV-projection + tiny attention + Wout fold -> Tmb.
// Grid 128, 256 thr. GEMM 96x128xK256: Wqkv-slice (48KB) + XRbT-slice (64KB)
// staged wholly in LDS (glds, swizzled), 96 MFMA/wave; bias = bqkv·sP; only
// the needed halves (q×Rq, k/v×Rk) written to compact qf[96][64]. Then k4b's
// verified attention path. LDS regions reused across a barrier.
// ---------------------------------------------------------------------------
__global__ __launch_bounds__(256) void k4f_attn(const ushort_t* __restrict__ Wqkvb,
                                                const ushort_t* __restrict__ XRbT,
                                                const float* __restrict__ bqkv,
                                                const float* __restrict__ sP,
                                                const float* __restrict__ Wout,
                                                ushort_t* __restrict__ Tmb) {
  __shared__ __align__(16) char SHRAW[114688];  // 112 KB
  ushort_t* Aw = (ushort_t*)SHRAW;              // 96 x 256 (49152 B)
  ushort_t* Bw = (ushort_t*)(SHRAW + 49152);    // 128 x 256 (65536 B)
  float* qf = (float*)SHRAW;                    // reuse: 96 x 64 (24576 B)
  float* attn_sT = (float*)(SHRAW + 24576);     // 64 x 65 (16640 B)
  float* vals_s = (float*)(SHRAW + 41216);      // 32 x 64 (8192 B)
  const int b = blockIdx.x >> 3, h = blockIdx.x & 7;
  const int tid = threadIdx.x;
  const int l = tid & 63, w = tid >> 6;
  const ushort_t* Asrc = Wqkvb + (size_t)(h * 96) * NC;
  const ushort_t* Bsrc = XRbT + ((size_t)b * NP + h * 128) * NC;
  // stage: each glds covers 2 rows (64 lanes x 16B = 1024B = 2x512B rows)
  {
    const int r2 = l >> 5;   // sub-row 0/1
    const int oct = l & 31;  // 16B octet within row
#pragma unroll
    for (int i = 0; i < 12; i++) {
      const int rbase = (i * 4 + w) * 2;
      const int row = rbase + r2;
      const int scol = (oct ^ (row & 7)) * 8;  // inverse-swizzled source col
      glds16(Asrc + (size_t)row * NC + scol, Aw + rbase * 256);
    }
#pragma unroll
    for (int i = 0; i < 16; i++) {
      const int rbase = (i * 4 + w) * 2;
      const int row = rbase + r2;
      const int scol = (oct ^ (row & 7)) * 8;
      glds16(Bsrc + (size_t)row * NC + scol, Bw + rbase * 256);
    }
  }
  __syncthreads();
  // GEMM: wave w -> p-local cols w*32..+32 (2 fragments), all 6 m-fragments
  const int fr = l & 15, kq = (l >> 4) * 8;
  const int swz = (fr & 7) << 3;
  f32x4 acc[6][2] = {};
#pragma unroll
  for (int ks = 0; ks < 8; ks++) {
    const int col = ks * 32 + kq;
    bf16x8 bf[2];
#pragma unroll
    for (int f = 0; f < 2; f++)
      bf[f] = *(const bf16x8*)&Bw[(w * 32 + f * 16 + fr) * 256 + (col ^ swz)];
#pragma unroll
    for (int fm = 0; fm < 6; fm++) {
      bf16x8 af = *(const bf16x8*)&Aw[(fm * 16 + fr) * 256 + (col ^ swz)];
#pragma unroll
      for (int f = 0; f < 2; f++) acc[fm][f] = mfma16(af, bf[f], acc[fm][f]);
    }
  }
  __syncthreads();  // done reading Aw/Bw; regions reused for qf/attn
  // bias + compact qf write (waves 0,1: q rows x Rq; waves 2,3: k/v rows x Rk)
  {
    const int rb = (l >> 4) * 4;
    float spv[2];
#pragma unroll
    for (int f = 0; f < 2; f++)
      spv[f] = sP[(size_t)b * NP + h * 128 + w * 32 + f * 16 + fr];
    if (w < 2) {
#pragma unroll
      for (int fm = 0; fm < 2; fm++)
#pragma unroll
        for (int rg = 0; rg < 4; rg++) {
          const int row = fm * 16 + rb + rg;
          const float bq = bqkv[h * 96 + row];
#pragma unroll
          for (int f = 0; f < 2; f++)
            qf[row * 64 + w * 32 + f * 16 + fr] = acc[fm][f][rg] + bq * spv[f];
        }
    } else {
#pragma unroll
      for (int fm = 2; fm < 6; fm++)
#pragma unroll
        for (int rg = 0; rg < 4; rg++) {
          const int row = fm * 16 + rb + rg;
          const float bq = bqkv[h * 96 + row];
#pragma unroll
          for (int f = 0; f < 2; f++)
            qf[row * 64 + (w - 2) * 32 + f * 16 + fr] = acc[fm][f][rg] + bq * spv[f];
        }
    }
  }
  __syncthreads();
  // attention (k4b's verified path)
  const int lj = tid & 63;
  const int rq = tid >> 6;
  float kcol[32];
#pragma unroll
  for (int dd = 0; dd < 32; dd++) kcol[dd] = qf[(32 + dd) * 64 + lj];
  const float isc = 0.17677669529663687f;
#pragma unroll
  for (int r = 0; r < 16; r++) {
    int qi = r * 4 + rq;
    float a = 0.f;
#pragma unroll
    for (int dd = 0; dd < 32; dd++) a += qf[dd * 64 + qi] * kcol[dd];
    attn_sT[lj * 65 + qi] = a * isc;
  }
  __syncthreads();
  if (tid < 64) {
    float m = -3e38f;
    for (int k = 0; k < 64; k++) m = fmaxf(m, attn_sT[k * 65 + tid]);
    float s = 0.f;
    for (int k = 0; k < 64; k++) {
      float e = __expf(attn_sT[k * 65 + tid] - m);
      attn_sT[k * 65 + tid] = e;
      s += e;
    }
    float inv = 1.f / s;
    for (int k = 0; k < 64; k++) attn_sT[k * 65 + tid] *= inv;
  }
  __syncthreads();
  float acol[64];
#pragma unroll
  for (int k = 0; k < 64; k++) acol[k] = attn_sT[k * 65 + lj];
#pragma unroll
  for (int r = 0; r < 8; r++) {
    int dd = r * 4 + rq;
    float a = 0.f;
#pragma unroll
    for (int k = 0; k < 64; k++) a += qf[(64 + dd) * 64 + k] * acol[k];
    vals_s[dd * 64 + lj] = a;
  }
  __syncthreads();
  float vcol[32];
#pragma unroll
  for (int dd = 0; dd < 32; dd++) vcol[dd] = vals_s[dd * 64 + lj];
  for (int r = 0; r < 64; r++) {
    int c = r * 4 + rq;
    const float4* wp = (const float4*)(Wout + (size_t)c * NC + h * 32);
    float a = 0.f;
#pragma unroll
    for (int t = 0; t < 8; t++) {
      float4 ww = wp[t];
      a += ww.x * vcol[t * 4] + ww.y * vcol[t * 4 + 1] + ww.z * vcol[t * 4 + 2] +
           ww.w * vcol[t * 4 + 3];
    }
    Tmb[((size_t)b * NC + c) * NT + h * 64 + lj] = f2b(a);
  }
}

// ---------------------------------------------------------------------------
// K5: out = x + alpha*(Tmb·Pq + bout). A glds dbuf (32KB); B reg-staged into
// SINGLE 18KB pad-72 LDS buffer (load-early / write-after-barrier) ->
// 51KB total -> 3 blocks/CU (was 2).
// ---------------------------------------------------------------------------
__global__ __launch_bounds__(256) void k5_out(const float* __restrict__ x,
                                              const ushort_t* __restrict__ P,
                                              const ushort_t* __restrict__ Tmb,
                                              const float* __restrict__ bout,
                                              const float* __restrict__ alpha,
                                              float* __restrict__ out) {
  __shared__ __align__(16) ushort_t Ash[2 * 8192];  // 32 KB
  __shared__ __align__(16) ushort_t Bsh[128 * 72];  // 18 KB single buffer
  const int tid = threadIdx.x;
  const int ord = blockIdx.x;
  const int L = (ord & 7) * 128 + (ord >> 3);
  const int m0 = (L & 1) * 128;
  const int n0 = ((L >> 1) & 31) * 128;
  const int b = L >> 6;
  const int lane = tid & 63, w = tid >> 6;
  const int wm = (w >> 1) * 64, wn = (w & 1) * 64;
  const int fr = lane & 15, kq = (lane >> 4) * 8;
  const int rr = lane >> 3, sc = ((lane & 7) ^ rr) << 3;
  const int swz = (fr & 7) << 3;
  const ushort_t* Asrc = Tmb + ((size_t)b * NC + m0) * NT;
  const int kg = tid >> 5, ng = (tid & 31) * 4;  // B stage: 8 k-rows x 4 n
  f32x4 acc[4][4] = {};
  ushort4_t bv[8];

  auto A_STAGE = [&](int bi, int k0) {
    ushort_t* Ad = Ash + bi * 8192;
#pragma unroll
    for (int i = 0; i < 4; i++) {
      const int row = i * 32 + w * 8 + rr;
      glds16(Asrc + (size_t)row * NT + k0 + sc, Ad + (i * 32 + w * 8) * 64);
    }
  };
  auto B_LOAD = [&](int k0) {
#pragma unroll
    for (int i = 0; i < 8; i++) {
      int hj = k0 + kg * 8 + i;
      int prow = ((hj >> 6) << 7) + (hj & 63);
      bv[i] = *(const ushort4_t*)(P + ((size_t)b * NP + prow) * NN + n0 + ng);
    }
  };
  auto B_WRITE = [&]() {
#pragma unroll
    for (int jj = 0; jj < 4; jj++) {
      ushort8_t pk;
#pragma unroll
      for (int i = 0; i < 8; i++) pk[i] = bv[i][jj];
      *(ushort8_t*)&Bsh[(ng + jj) * 72 + kg * 8] = pk;
    }
  };

  B_LOAD(0);
  A_STAGE(0, 0);
  B_WRITE();       // no prior readers of Bsh; waits only on bv loads
  __syncthreads();
  int acur = 0;
#pragma unroll 1
  for (int it = 0; it < 8; it++) {
    if (it < 7) {
      B_LOAD((it + 1) * 64);
      A_STAGE(acur ^ 1, (it + 1) * 64);
    }
    const ushort_t* Ar = Ash + acur * 8192;
#pragma unroll
    for (int ks = 0; ks < 2; ks++) {
      const int col = ks * 32 + kq;
      bf16x8 af[4], bf[4];
#pragma unroll
      for (int f = 0; f < 4; f++) {
        af[f] = *(const bf16x8*)&Ar[(wm + f * 16 + fr) * 64 + (col ^ swz)];
        bf[f] = *(const bf16x8*)&Bsh[(wn + f * 16 + fr) * 72 + col];
      }
#pragma unroll
      for (int fm = 0; fm < 4; fm++)
#pragma unroll
        for (int fn = 0; fn < 4; fn++)
          acc[fm][fn] = mfma16(af[fm], bf[fn], acc[fm][fn]);
    }
    __syncthreads();             // all readers done with Bsh (+A drains)
    if (it < 7) {
      B_WRITE();                 // t+1 image into the single buffer
      __syncthreads();           // visible before next compute
    }
    acur ^= 1;
  }
  const float al = alpha[0];
  const int col = lane & 15, rb = (lane >> 4) * 4;
#pragma unroll
  for (int fm = 0; fm < 4; fm++)
#pragma unroll
    for (int rg = 0; rg < 4; rg++) {
      int row = m0 + wm + fm * 16 + rb + rg;
      float bias = bout[row];
#pragma unroll
      for (int fn = 0; fn < 4; fn++) {
        int cc = n0 + wn + fn * 16 + col;
        size_t idx = ((size_t)b * NC + row) * NN + cc;
        out[idx] = x[idx] + al * (acc[fm][fn][rg] + bias);
      }
    }
}

// ---------------------------------------------------------------------------
extern "C" void kernel_launch(void* const* d_in, const int* in_sizes, int n_in,
                              void* d_out, int out_size, void* d_ws, size_t ws_size,
                              hipStream_t stream) {
  const float* x = (const float*)d_in[0];
  const float* Wqkv = (const float*)d_in[1];
  const float* bqkv = (const float*)d_in[2];
  const float* Wr = (const float*)d_in[3];
  const float* br = (const float*)d_in[4];
  const float* Wout = (const float*)d_in[5];
  const float* bout = (const float*)d_in[6];
  const float* alpha = (const float*)d_in[7];
  float* out = (float*)d_out;

  char* ws = (char*)d_ws;
  ushort_t* P = (ushort_t*)ws;                    // [0, 134217728)
  ushort_t* xb = (ushort_t*)(ws + 134217728);     // 33.5MB (dead after k3)
  ushort_t* xt = (ushort_t*)(ws + 167772160);     // 33.5MB (dead after k1)
  ushort_t* XRbT = (ushort_t*)(ws + 167772160);   //   aliases xt: 8.4MB (k3+)
  ushort_t* Wrb = (ushort_t*)(ws + 201326592);    // 0.5MB
  float* sPpart = (float*)(ws + 201850880);       // 4.2MB (dead after k2r)
  ushort_t* Wqkvb = (ushort_t*)(ws + 201850880);  //   aliases sPpart: 0.4MB
  float* sP = (float*)(ws + 206045184);           // 64KB
  ushort_t* Tmb = (ushort_t*)(ws + 206110720);    // 4.2MB -> end 210305024

  k0_cvt<<<dim3(64, 4, 16), 256, 0, stream>>>(x, xb, xt);
  cvt_f2b_k<<<256, 256, 0, stream>>>(Wr, Wrb);
  k1_proj<<<4096, 256, 0, stream>>>(Wrb, xt, br, P);
  k2_softmax<<<dim3(64, 16), 512, 0, stream>>>(P, sPpart);
  k2r_reduce<<<64, 256, 0, stream>>>(sPpart, sP);
  cvt_f2b_k<<<192, 256, 0, stream>>>(Wqkv, Wqkvb);  // after k2r (aliases sPpart)
  k3_pool<<<256, 256, 0, stream>>>(xb, P, XRbT);    // writes into xt region (xt dead)
  k4f_attn<<<128, 256, 0, stream>>>(Wqkvb, XRbT, bqkv, sP, Wout, Tmb);
  k5_out<<<1024, 256, 0, stream>>>(x, P, Tmb, bout, alpha, out);
}